// Round 8
// baseline (410.647 us; speedup 1.0000x reference)
//
#include <hip/hip_runtime.h>
#include <hip/hip_fp16.h>
#include <cstdint>
#include <cstddef>

// GAT 3-layer forward for MI355X — round 8.
// Changes vs round 7 (403us):
//  * k_fused256: manual unroll x2 over the edge-slot stride -> 8 independent
//    gather chains/wave (was latency-bound: VALU 41%, HBM 46%, neither
//    saturated).
//  * k_fused_out: 4 edge slots x 4 lanes (16 lanes/node) — same ILP treatment.
//  * layer-2 el/er folded into k_mfma_gemm32 via WLR2 (cols 0/1 = W2·al2 /
//    W2·ar2) — k_elr1 deleted.

#define IN_FEATS 128

typedef _Float16 f16x8 __attribute__((ext_vector_type(8)));
typedef _Float16 f16x4 __attribute__((ext_vector_type(4)));
typedef float f32x4 __attribute__((ext_vector_type(4)));

// ---------- fp32 -> fp16 cast (8 elems/thread) ----------
__global__ __launch_bounds__(256) void k_f2h(const float* __restrict__ in,
                                             _Float16* __restrict__ out, int n8) {
    int i = blockIdx.x * 256 + threadIdx.x;
    if (i >= n8) return;
    float4 v0 = *(const float4*)(in + (size_t)i * 8);
    float4 v1 = *(const float4*)(in + (size_t)i * 8 + 4);
    f16x8 o;
    o[0] = (_Float16)v0.x; o[1] = (_Float16)v0.y;
    o[2] = (_Float16)v0.z; o[3] = (_Float16)v0.w;
    o[4] = (_Float16)v1.x; o[5] = (_Float16)v1.y;
    o[6] = (_Float16)v1.z; o[7] = (_Float16)v1.w;
    *(f16x8*)(out + (size_t)i * 8) = o;
}

// ---------- W [K][N] fp32 -> WT [N][K] fp16 ----------
__global__ __launch_bounds__(256) void k_wt(const float* __restrict__ W,
                                            _Float16* __restrict__ WT, int K, int N) {
    int i = blockIdx.x * 256 + threadIdx.x;
    if (i >= K * N) return;
    int nn = i / K, kk = i - nn * K;
    WT[i] = (_Float16)W[(size_t)kk * N + nn];
}

// ---------- WLR[16][K]: rows 0..7 = W·al_h, rows 8..15 = W·ar_h (H=8,C=32) ----------
__global__ __launch_bounds__(256) void k_wlr(const float* __restrict__ W,
                                             const float* __restrict__ al,
                                             const float* __restrict__ ar,
                                             _Float16* __restrict__ WLRT,
                                             int K, int N) {
    int i = blockIdx.x * 256 + threadIdx.x;
    if (i >= K * 16) return;
    int j = i / K, k = i - j * K;          // j in [0,16)
    int h = j & 7;
    const float* av = (j < 8) ? al : ar;
    float sum = 0.f;
    #pragma unroll 8
    for (int c = 0; c < 32; ++c) sum += W[(size_t)k * N + h * 32 + c] * av[h * 32 + c];
    WLRT[(size_t)j * K + k] = (_Float16)sum;
}

// ---------- WLR2[16][K] for H=1,C=32: row0 = W·al, row1 = W·ar, rows 2..15 = 0 ----------
__global__ __launch_bounds__(256) void k_wlr2(const float* __restrict__ W,
                                              const float* __restrict__ al,
                                              const float* __restrict__ ar,
                                              _Float16* __restrict__ WLRT, int K) {
    int i = blockIdx.x * 256 + threadIdx.x;
    if (i >= K * 16) return;
    int j = i / K, k = i - j * K;
    float sum = 0.f;
    if (j < 2) {
        const float* av = (j == 0) ? al : ar;
        #pragma unroll 8
        for (int c = 0; c < 32; ++c) sum += W[(size_t)k * 32 + c] * av[c];
    }
    WLRT[(size_t)j * K + k] = (_Float16)sum;
}

// ---------- MFMA GEMM, N=256, A via LDS; wave 3 also emits el/er ----------
template <int K>
__global__ __launch_bounds__(256) void k_mfma_gemm(const _Float16* __restrict__ A,
                                                   const _Float16* __restrict__ BT,
                                                   const _Float16* __restrict__ WLRT,
                                                   _Float16* __restrict__ C,
                                                   float* __restrict__ el,
                                                   float* __restrict__ er, int M) {
    const int N = 256;
    const int LDA = K + 8;
    __shared__ _Float16 As[64 * LDA];
    int tid = threadIdx.x;
    int lane = tid & 63, wc = tid >> 6;
    int mr = blockIdx.x * 64;
    #pragma unroll
    for (int it = 0; it < K / 32; ++it) {
        int idx = (it * 256 + tid) * 8;
        int row = idx / K, col = idx % K;
        int rowg = mr + row; if (rowg > M - 1) rowg = M - 1;
        f16x8 v = *(const f16x8*)(A + (size_t)rowg * K + col);
        *(f16x8*)(As + row * LDA + col) = v;
    }
    __syncthreads();
    const _Float16* pb[4];
    #pragma unroll
    for (int j = 0; j < 4; ++j) {
        int col = wc * 64 + j * 16 + (lane & 15);
        pb[j] = BT + (size_t)col * K + (lane >> 4) * 8;
    }
    const _Float16* pe = WLRT + (size_t)(lane & 15) * K + (lane >> 4) * 8;
    const _Float16* pa = As + (lane & 15) * LDA + (lane >> 4) * 8;
    f32x4 acc[4][4] = {};
    f32x4 acce[4] = {};
    #pragma unroll
    for (int k0 = 0; k0 < K; k0 += 32) {
        f16x8 a[4], b[4];
        #pragma unroll
        for (int t = 0; t < 4; ++t) a[t] = *(const f16x8*)(pa + t * 16 * LDA + k0);
        #pragma unroll
        for (int t = 0; t < 4; ++t) b[t] = *(const f16x8*)(pb[t] + k0);
        #pragma unroll
        for (int i = 0; i < 4; ++i)
            #pragma unroll
            for (int j = 0; j < 4; ++j)
                acc[i][j] = __builtin_amdgcn_mfma_f32_16x16x32_f16(a[i], b[j], acc[i][j], 0, 0, 0);
        if (wc == 3) {
            f16x8 be = *(const f16x8*)(pe + k0);
            #pragma unroll
            for (int i = 0; i < 4; ++i)
                acce[i] = __builtin_amdgcn_mfma_f32_16x16x32_f16(a[i], be, acce[i], 0, 0, 0);
        }
    }
    // C/D layout: col = lane&15, row = (lane>>4)*4 + reg
    #pragma unroll
    for (int i = 0; i < 4; ++i)
        #pragma unroll
        for (int j = 0; j < 4; ++j)
            #pragma unroll
            for (int r = 0; r < 4; ++r) {
                int row = mr + i * 16 + (lane >> 4) * 4 + r;
                int col = wc * 64 + j * 16 + (lane & 15);
                if (row < M) C[(size_t)row * N + col] = (_Float16)acc[i][j][r];
            }
    if (wc == 3) {
        int c16 = lane & 15;
        #pragma unroll
        for (int i = 0; i < 4; ++i)
            #pragma unroll
            for (int r = 0; r < 4; ++r) {
                int row = mr + i * 16 + (lane >> 4) * 4 + r;
                if (row < M) {
                    if (c16 < 8) el[row * 8 + c16] = acce[i][r];
                    else         er[row * 8 + (c16 - 8)] = acce[i][r];
                }
            }
    }
}

// ---------- MFMA GEMM, N=32 (layer 2), fused el/er via WLR2 ----------
template <int K>
__global__ __launch_bounds__(256) void k_mfma_gemm32(const _Float16* __restrict__ A,
                                                     const _Float16* __restrict__ BT,
                                                     const _Float16* __restrict__ WLRT,
                                                     _Float16* __restrict__ C,
                                                     float* __restrict__ el,
                                                     float* __restrict__ er, int M) {
    const int N = 32;
    int lane = threadIdx.x & 63, w = threadIdx.x >> 6;
    int mr = blockIdx.x * 256 + w * 64;
    const _Float16* pa[4];
    const _Float16* pb[2];
    #pragma unroll
    for (int t = 0; t < 4; ++t) {
        int row = mr + t * 16 + (lane & 15);
        if (row > M - 1) row = M - 1;
        pa[t] = A + (size_t)row * K + (lane >> 4) * 8;
    }
    #pragma unroll
    for (int t = 0; t < 2; ++t) {
        int col = t * 16 + (lane & 15);
        pb[t] = BT + (size_t)col * K + (lane >> 4) * 8;
    }
    const _Float16* pe = WLRT + (size_t)(lane & 15) * K + (lane >> 4) * 8;
    f32x4 acc[4][2] = {};
    f32x4 acce[4] = {};
    #pragma unroll
    for (int k0 = 0; k0 < K; k0 += 32) {
        f16x8 a[4], b[2], be;
        #pragma unroll
        for (int t = 0; t < 4; ++t) a[t] = *(const f16x8*)(pa[t] + k0);
        #pragma unroll
        for (int t = 0; t < 2; ++t) b[t] = *(const f16x8*)(pb[t] + k0);
        be = *(const f16x8*)(pe + k0);
        #pragma unroll
        for (int i = 0; i < 4; ++i) {
            #pragma unroll
            for (int j = 0; j < 2; ++j)
                acc[i][j] = __builtin_amdgcn_mfma_f32_16x16x32_f16(a[i], b[j], acc[i][j], 0, 0, 0);
            acce[i] = __builtin_amdgcn_mfma_f32_16x16x32_f16(a[i], be, acce[i], 0, 0, 0);
        }
    }
    int c16 = lane & 15;
    #pragma unroll
    for (int i = 0; i < 4; ++i)
        #pragma unroll
        for (int r = 0; r < 4; ++r) {
            int row = mr + i * 16 + (lane >> 4) * 4 + r;
            if (row < M) {
                #pragma unroll
                for (int j = 0; j < 2; ++j)
                    C[(size_t)row * N + j * 16 + c16] = (_Float16)acc[i][j][r];
                if (c16 == 0) el[row] = acce[i][r];
                else if (c16 == 1) er[row] = acce[i][r];
            }
        }
}

// ---------- CSR build ----------
__global__ void k_deg(const int* __restrict__ dst, int* __restrict__ deg, int E) {
    int e = blockIdx.x * blockDim.x + threadIdx.x;
    if (e < E) atomicAdd(deg + dst[e], 1);
}
__global__ __launch_bounds__(256) void k_scan1(const int* __restrict__ deg,
                                               int* __restrict__ bsum, int n) {
    int base = blockIdx.x * 1024;
    int t = threadIdx.x;
    int s = 0;
    #pragma unroll
    for (int i = 0; i < 4; ++i) {
        int idx = base + t * 4 + i;
        if (idx < n) s += deg[idx];
    }
    __shared__ int red[256];
    red[t] = s; __syncthreads();
    for (int off = 128; off; off >>= 1) {
        if (t < off) red[t] += red[t + off];
        __syncthreads();
    }
    if (t == 0) bsum[blockIdx.x] = red[0];
}
__global__ __launch_bounds__(64) void k_scan2(int* __restrict__ bsum, int nb,
                                              int* __restrict__ row_ptr, int n, int E) {
    int t = threadIdx.x;
    int v = (t < nb) ? bsum[t] : 0;
    int x = v;
    #pragma unroll
    for (int off = 1; off < 64; off <<= 1) {
        int y = __shfl_up(x, off, 64);
        if (t >= off) x += y;
    }
    if (t < nb) bsum[t] = x - v;   // exclusive
    if (t == 0) row_ptr[n] = E;
}
__global__ __launch_bounds__(256) void k_scan3(const int* __restrict__ deg,
                                               const int* __restrict__ bsum,
                                               int* __restrict__ row_ptr, int n) {
    int base = blockIdx.x * 1024;
    int t = threadIdx.x;
    int loc[4]; int s = 0;
    #pragma unroll
    for (int i = 0; i < 4; ++i) {
        int idx = base + t * 4 + i;
        loc[i] = (idx < n) ? deg[idx] : 0;
        s += loc[i];
    }
    __shared__ int part[256];
    part[t] = s; __syncthreads();
    for (int off = 1; off < 256; off <<= 1) {
        int v = (t >= off) ? part[t - off] : 0;
        __syncthreads();
        part[t] += v;
        __syncthreads();
    }
    int run = bsum[blockIdx.x] + part[t] - s;
    #pragma unroll
    for (int i = 0; i < 4; ++i) {
        int idx = base + t * 4 + i;
        if (idx < n) row_ptr[idx] = run;
        run += loc[i];
    }
}
__global__ void k_fill(const int* __restrict__ dst, const int* __restrict__ src,
                       const int* __restrict__ row_ptr,
                       int* __restrict__ fill, int* __restrict__ csrc, int E) {
    int e = blockIdx.x * blockDim.x + threadIdx.x;
    if (e < E) {
        int d = dst[e];
        int pos = row_ptr[d] + atomicAdd(fill + d, 1);
        csrc[pos] = src[e];
    }
}

// ---------- fused softmax aggregation, H=8,C=32: single pass, no max ----------
// One wave per node; 4 edge slots x 16 lanes; unroll x2 -> 8 gathers in flight.
__global__ __launch_bounds__(256) void k_fused256(const int* __restrict__ row_ptr,
                                                  const int* __restrict__ csrc,
                                                  const float* __restrict__ el,
                                                  const float* __restrict__ er,
                                                  const _Float16* __restrict__ ft16,
                                                  const float* __restrict__ b,
                                                  _Float16* __restrict__ out, int n) {
    int wave = threadIdx.x >> 6;
    int lane = threadIdx.x & 63;
    int v = blockIdx.x * 4 + wave;
    if (v >= n) return;
    int g = lane >> 4;            // edge slot 0..3
    int l16 = lane & 15;          // channel group: 16 ch each
    int h = l16 >> 1;             // head (2 lanes per head)
    float erv = er[v * 8 + h];
    const float* elh = el + h;
    int e0 = row_ptr[v], e1 = row_ptr[v + 1];
    float s = 0.f;
    float a[16] = {};
    int k = e0 + g;
    for (; k + 4 < e1; k += 8) {
        int sn0 = csrc[k];
        int sn1 = csrc[k + 4];
        float ev0 = elh[sn0 * 8] + erv;
        float ev1 = elh[sn1 * 8] + erv;
        ev0 = ev0 > 0.f ? ev0 : 0.2f * ev0;
        ev1 = ev1 > 0.f ? ev1 : 0.2f * ev1;
        float w0 = __expf(ev0);
        float w1 = __expf(ev1);
        const _Float16* fp0 = ft16 + (sn0 << 8) + l16 * 16;
        const _Float16* fp1 = ft16 + (sn1 << 8) + l16 * 16;
        f16x8 f00 = *(const f16x8*)fp0;
        f16x8 f01 = *(const f16x8*)(fp0 + 8);
        f16x8 f10 = *(const f16x8*)fp1;
        f16x8 f11 = *(const f16x8*)(fp1 + 8);
        s += w0 + w1;
        #pragma unroll
        for (int j = 0; j < 8; ++j) a[j] += w0 * (float)f00[j];
        #pragma unroll
        for (int j = 0; j < 8; ++j) a[8 + j] += w0 * (float)f01[j];
        #pragma unroll
        for (int j = 0; j < 8; ++j) a[j] += w1 * (float)f10[j];
        #pragma unroll
        for (int j = 0; j < 8; ++j) a[8 + j] += w1 * (float)f11[j];
    }
    if (k < e1) {
        int sn = csrc[k];
        float ev = elh[sn * 8] + erv;
        ev = ev > 0.f ? ev : 0.2f * ev;
        float w = __expf(ev);
        s += w;
        const _Float16* fp = ft16 + (sn << 8) + l16 * 16;
        f16x8 f0 = *(const f16x8*)fp;
        f16x8 f1 = *(const f16x8*)(fp + 8);
        #pragma unroll
        for (int j = 0; j < 8; ++j) a[j] += w * (float)f0[j];
        #pragma unroll
        for (int j = 0; j < 8; ++j) a[8 + j] += w * (float)f1[j];
    }
    // ---- merge the 4 slots ----
    s += __shfl_xor(s, 16, 64);
    s += __shfl_xor(s, 32, 64);
    #pragma unroll
    for (int j = 0; j < 16; ++j) {
        a[j] += __shfl_xor(a[j], 16, 64);
        a[j] += __shfl_xor(a[j], 32, 64);
    }
    if (g == 0) {
        float inv = s > 0.f ? 1.f / s : 0.f;
        const float* bp = b + l16 * 16;
        f16x8 o0, o1;
        #pragma unroll
        for (int j = 0; j < 8; ++j) o0[j] = (_Float16)fmaxf(a[j] * inv + bp[j], 0.f);
        #pragma unroll
        for (int j = 0; j < 8; ++j) o1[j] = (_Float16)fmaxf(a[8 + j] * inv + bp[8 + j], 0.f);
        _Float16* op = out + ((size_t)v << 8) + l16 * 16;
        *(f16x8*)op = o0;
        *(f16x8*)(op + 8) = o1;
    }
}

// ---------- fused aggregation, H=1,C=32 (layer 2) + class softmax ----------
// 16 lanes per node: 4 edge slots x 4 lanes; lane covers 8 channels (16B).
__global__ __launch_bounds__(256) void k_fused_out(const int* __restrict__ row_ptr,
                                                   const int* __restrict__ csrc,
                                                   const float* __restrict__ el,
                                                   const float* __restrict__ er,
                                                   const _Float16* __restrict__ ft,
                                                   const float* __restrict__ b,
                                                   float* __restrict__ out, int n) {
    int v = blockIdx.x * 16 + (threadIdx.x >> 4);
    int sub = threadIdx.x & 15;
    int g = sub >> 2;             // edge slot 0..3
    int l4 = sub & 3;             // channel group: 8 ch each
    if (v >= n) return;
    float erv = er[v];
    int e0 = row_ptr[v], e1 = row_ptr[v + 1];
    float s = 0.f;
    float a[8] = {};
    for (int k = e0 + g; k < e1; k += 4) {
        int sn = csrc[k];
        float ev = el[sn] + erv;
        ev = ev > 0.f ? ev : 0.2f * ev;
        float w = __expf(ev);
        s += w;
        f16x8 f = *(const f16x8*)(ft + (sn << 5) + l4 * 8);
        #pragma unroll
        for (int j = 0; j < 8; ++j) a[j] += w * (float)f[j];
    }
    s += __shfl_xor(s, 4, 64);
    s += __shfl_xor(s, 8, 64);
    #pragma unroll
    for (int j = 0; j < 8; ++j) {
        a[j] += __shfl_xor(a[j], 4, 64);
        a[j] += __shfl_xor(a[j], 8, 64);
    }
    float inv = s > 0.f ? 1.f / s : 0.f;
    const float* bp = b + l4 * 8;
    float val[8];
    float mx = -INFINITY;
    #pragma unroll
    for (int j = 0; j < 8; ++j) {
        val[j] = fmaxf(a[j] * inv + bp[j], 0.f);
        mx = fmaxf(mx, val[j]);
    }
    mx = fmaxf(mx, __shfl_xor(mx, 1, 64));
    mx = fmaxf(mx, __shfl_xor(mx, 2, 64));
    float ex[8];
    float sum = 0.f;
    #pragma unroll
    for (int j = 0; j < 8; ++j) { ex[j] = __expf(val[j] - mx); sum += ex[j]; }
    sum += __shfl_xor(sum, 1, 64);
    sum += __shfl_xor(sum, 2, 64);
    float isum = 1.f / sum;
    if (g == 0) {
        float* op = out + ((size_t)v << 5) + l4 * 8;
        *(float4*)op = make_float4(ex[0] * isum, ex[1] * isum, ex[2] * isum, ex[3] * isum);
        *(float4*)(op + 4) = make_float4(ex[4] * isum, ex[5] * isum, ex[6] * isum, ex[7] * isum);
    }
}

extern "C" void kernel_launch(void* const* d_in, const int* in_sizes, int n_in,
                              void* d_out, int out_size, void* d_ws, size_t ws_size,
                              hipStream_t stream) {
    const float* x  = (const float*)d_in[0];
    const int* src  = (const int*)d_in[1];
    const int* dst  = (const int*)d_in[2];
    const float* W0 = (const float*)d_in[3];
    const float* al0 = (const float*)d_in[4];
    const float* ar0 = (const float*)d_in[5];
    const float* b0  = (const float*)d_in[6];
    const float* W1 = (const float*)d_in[7];
    const float* al1 = (const float*)d_in[8];
    const float* ar1 = (const float*)d_in[9];
    const float* b1  = (const float*)d_in[10];
    const float* W2 = (const float*)d_in[11];
    const float* al2 = (const float*)d_in[12];
    const float* ar2 = (const float*)d_in[13];
    const float* b2  = (const float*)d_in[14];
    float* out = (float*)d_out;

    const int n = in_sizes[0] / IN_FEATS;   // 50000
    const int E = in_sizes[1];              // 800000

    // ---- workspace carve (256B-aligned) ----
    char* p = (char*)d_ws;
    auto alloc = [&](size_t bytes) {
        void* r = (void*)p;
        p += (bytes + 255) & ~(size_t)255;
        return r;
    };
    _Float16* ft16  = (_Float16*)alloc((size_t)n * 256 * 2);
    _Float16* h16   = (_Float16*)alloc((size_t)n * 256 * 2);
    _Float16* x16   = (_Float16*)alloc((size_t)n * 128 * 2);
    _Float16* W0T   = (_Float16*)alloc((size_t)256 * 128 * 2);
    _Float16* W1T   = (_Float16*)alloc((size_t)256 * 256 * 2);
    _Float16* W2T   = (_Float16*)alloc((size_t)32 * 256 * 2);
    _Float16* WLR0  = (_Float16*)alloc((size_t)16 * 128 * 2);
    _Float16* WLR1  = (_Float16*)alloc((size_t)16 * 256 * 2);
    _Float16* WLR2  = (_Float16*)alloc((size_t)16 * 256 * 2);
    float* el       = (float*)alloc((size_t)n * 8 * 4);
    float* er       = (float*)alloc((size_t)n * 8 * 4);
    int* deg        = (int*)alloc((size_t)n * 4);
    int* fill       = (int*)alloc((size_t)n * 4);
    int* row_ptr    = (int*)alloc((size_t)(n + 1) * 4);
    int* csrc       = (int*)alloc((size_t)E * 4);
    int* bsum       = (int*)alloc((size_t)64 * 4);

    const int EB = (E + 255) / 256;
    const int NBCH = (n + 1023) / 1024;     // scan blocks (49 <= 64)

    // ---- CSR by dst (shared by all 3 layers) ----
    hipMemsetAsync(deg, 0, (size_t)n * 4, stream);
    hipMemsetAsync(fill, 0, (size_t)n * 4, stream);
    k_deg<<<EB, 256, 0, stream>>>(dst, deg, E);
    k_scan1<<<NBCH, 256, 0, stream>>>(deg, bsum, n);
    k_scan2<<<1, 64, 0, stream>>>(bsum, NBCH, row_ptr, n, E);
    k_scan3<<<NBCH, 256, 0, stream>>>(deg, bsum, row_ptr, n);
    k_fill<<<EB, 256, 0, stream>>>(dst, src, row_ptr, fill, csrc, E);

    // ---- weight prep ----
    k_f2h<<<(n * 128 / 8 + 255) / 256, 256, 0, stream>>>(x, x16, n * 128 / 8);
    k_wt<<<(128 * 256 + 255) / 256, 256, 0, stream>>>(W0, W0T, 128, 256);
    k_wt<<<(256 * 256 + 255) / 256, 256, 0, stream>>>(W1, W1T, 256, 256);
    k_wt<<<(256 * 32 + 255) / 256, 256, 0, stream>>>(W2, W2T, 256, 32);
    k_wlr<<<(128 * 16 + 255) / 256, 256, 0, stream>>>(W0, al0, ar0, WLR0, 128, 256);
    k_wlr<<<(256 * 16 + 255) / 256, 256, 0, stream>>>(W1, al1, ar1, WLR1, 256, 256);
    k_wlr2<<<(256 * 16 + 255) / 256, 256, 0, stream>>>(W2, al2, ar2, WLR2, 256);

    const int GB = (n + 63) / 64;
    const int GB32 = (n + 255) / 256;
    const int FB = (n + 3) / 4;
    const int OB = (n + 15) / 16;

    // ---- layer 0 ----
    k_mfma_gemm<128><<<GB, 256, 0, stream>>>(x16, W0T, WLR0, ft16, el, er, n);
    k_fused256<<<FB, 256, 0, stream>>>(row_ptr, csrc, el, er, ft16, b0, h16, n);

    // ---- layer 1 ----
    k_mfma_gemm<256><<<GB, 256, 0, stream>>>(h16, W1T, WLR1, ft16, el, er, n);
    k_fused256<<<FB, 256, 0, stream>>>(row_ptr, csrc, el, er, ft16, b1, h16, n);

    // ---- layer 2 + class softmax ----
    k_mfma_gemm32<256><<<GB32, 256, 0, stream>>>(h16, W2T, WLR2, ft16, el, er, n);
    k_fused_out<<<OB, 256, 0, stream>>>(row_ptr, csrc, el, er, ft16, b2, out, n);
}

// Round 9
// 380.398 us; speedup vs baseline: 1.0795x; 1.0795x over previous
//
#include <hip/hip_runtime.h>
#include <hip/hip_fp16.h>
#include <cstdint>
#include <cstddef>

// GAT 3-layer forward for MI355X — round 9 (consolidation).
// Changes vs round 8 (411us):
//  * k_fused256 declared at its gather ceiling (12.6 B/cy/CU streaming; ILP
//    flat in round 8) — untouched.
//  * A-cast folded into GEMM staging (template on A dtype): k_f2h + x16 gone.
//  * Single k_prep kernel for all 6 weight transforms.
//  * CSR: scan2 folded into scan3; two memsets merged into one.
//  Dispatches: 24 -> 12.

#define IN_FEATS 128

typedef _Float16 f16x8 __attribute__((ext_vector_type(8)));
typedef float f32x4 __attribute__((ext_vector_type(4)));

// ---------- merged weight prep ----------
// blocks [0,128)   : W0T  [256][128] <- W0 [128][256]
// blocks [128,384) : W1T  [256][256] <- W1 [256][256]
// blocks [384,416) : W2T  [32][256]  <- W2 [256][32]
// blocks [416,424) : WLR0 [16][128]  (rows 0-7 W0·al0_h, 8-15 W0·ar0_h)
// blocks [424,440) : WLR1 [16][256]
// blocks [440,456) : WLR2 [16][256]  (row0 W2·al2, row1 W2·ar2, rest 0)
__global__ __launch_bounds__(256) void k_prep(
    const float* __restrict__ W0, const float* __restrict__ W1, const float* __restrict__ W2,
    const float* __restrict__ al0, const float* __restrict__ ar0,
    const float* __restrict__ al1, const float* __restrict__ ar1,
    const float* __restrict__ al2, const float* __restrict__ ar2,
    _Float16* __restrict__ W0T, _Float16* __restrict__ W1T, _Float16* __restrict__ W2T,
    _Float16* __restrict__ WLR0, _Float16* __restrict__ WLR1, _Float16* __restrict__ WLR2) {
    int bid = blockIdx.x, t = threadIdx.x;
    if (bid < 128) {                       // W0T: i over 256*128
        int i = bid * 256 + t;
        int nn = i >> 7, kk = i & 127;     // K=128, N=256
        W0T[i] = (_Float16)W0[(size_t)kk * 256 + nn];
    } else if (bid < 384) {                // W1T
        int i = (bid - 128) * 256 + t;
        int nn = i >> 8, kk = i & 255;     // K=256, N=256
        W1T[i] = (_Float16)W1[(size_t)kk * 256 + nn];
    } else if (bid < 416) {                // W2T
        int i = (bid - 384) * 256 + t;
        int nn = i >> 8, kk = i & 255;     // K=256, N=32
        W2T[i] = (_Float16)W2[(size_t)kk * 32 + nn];
    } else if (bid < 424) {                // WLR0: 16*128 elems
        int i = (bid - 416) * 256 + t;
        int j = i >> 7, k = i & 127;
        int h = j & 7;
        const float* av = (j < 8) ? al0 : ar0;
        float sum = 0.f;
        #pragma unroll 8
        for (int c = 0; c < 32; ++c) sum += W0[(size_t)k * 256 + h * 32 + c] * av[h * 32 + c];
        WLR0[i] = (_Float16)sum;
    } else if (bid < 440) {                // WLR1: 16*256
        int i = (bid - 424) * 256 + t;
        int j = i >> 8, k = i & 255;
        int h = j & 7;
        const float* av = (j < 8) ? al1 : ar1;
        float sum = 0.f;
        #pragma unroll 8
        for (int c = 0; c < 32; ++c) sum += W1[(size_t)k * 256 + h * 32 + c] * av[h * 32 + c];
        WLR1[i] = (_Float16)sum;
    } else {                               // WLR2: 16*256
        int i = (bid - 440) * 256 + t;
        int j = i >> 8, k = i & 255;
        float sum = 0.f;
        if (j < 2) {
            const float* av = (j == 0) ? al2 : ar2;
            #pragma unroll 8
            for (int c = 0; c < 32; ++c) sum += W2[(size_t)k * 32 + c] * av[c];
        }
        WLR2[i] = (_Float16)sum;
    }
}

// ---------- MFMA GEMM, N=256, A via LDS (cast during stage); wave 3 emits el/er ----------
template <int K, typename AT>
__global__ __launch_bounds__(256) void k_mfma_gemm(const AT* __restrict__ A,
                                                   const _Float16* __restrict__ BT,
                                                   const _Float16* __restrict__ WLRT,
                                                   _Float16* __restrict__ C,
                                                   float* __restrict__ el,
                                                   float* __restrict__ er, int M) {
    const int N = 256;
    const int LDA = K + 8;
    __shared__ _Float16 As[64 * LDA];
    int tid = threadIdx.x;
    int lane = tid & 63, wc = tid >> 6;
    int mr = blockIdx.x * 64;
    #pragma unroll
    for (int it = 0; it < K / 32; ++it) {
        int idx = (it * 256 + tid) * 8;
        int row = idx / K, col = idx % K;
        int rowg = mr + row; if (rowg > M - 1) rowg = M - 1;
        f16x8 v;
        if constexpr (sizeof(AT) == 2) {
            v = *(const f16x8*)(A + (size_t)rowg * K + col);
        } else {
            float4 u0 = *(const float4*)(A + (size_t)rowg * K + col);
            float4 u1 = *(const float4*)(A + (size_t)rowg * K + col + 4);
            v[0] = (_Float16)u0.x; v[1] = (_Float16)u0.y;
            v[2] = (_Float16)u0.z; v[3] = (_Float16)u0.w;
            v[4] = (_Float16)u1.x; v[5] = (_Float16)u1.y;
            v[6] = (_Float16)u1.z; v[7] = (_Float16)u1.w;
        }
        *(f16x8*)(As + row * LDA + col) = v;
    }
    __syncthreads();
    const _Float16* pb[4];
    #pragma unroll
    for (int j = 0; j < 4; ++j) {
        int col = wc * 64 + j * 16 + (lane & 15);
        pb[j] = BT + (size_t)col * K + (lane >> 4) * 8;
    }
    const _Float16* pe = WLRT + (size_t)(lane & 15) * K + (lane >> 4) * 8;
    const _Float16* pa = As + (lane & 15) * LDA + (lane >> 4) * 8;
    f32x4 acc[4][4] = {};
    f32x4 acce[4] = {};
    #pragma unroll
    for (int k0 = 0; k0 < K; k0 += 32) {
        f16x8 a[4], b[4];
        #pragma unroll
        for (int t = 0; t < 4; ++t) a[t] = *(const f16x8*)(pa + t * 16 * LDA + k0);
        #pragma unroll
        for (int t = 0; t < 4; ++t) b[t] = *(const f16x8*)(pb[t] + k0);
        #pragma unroll
        for (int i = 0; i < 4; ++i)
            #pragma unroll
            for (int j = 0; j < 4; ++j)
                acc[i][j] = __builtin_amdgcn_mfma_f32_16x16x32_f16(a[i], b[j], acc[i][j], 0, 0, 0);
        if (wc == 3) {
            f16x8 be = *(const f16x8*)(pe + k0);
            #pragma unroll
            for (int i = 0; i < 4; ++i)
                acce[i] = __builtin_amdgcn_mfma_f32_16x16x32_f16(a[i], be, acce[i], 0, 0, 0);
        }
    }
    // C/D layout: col = lane&15, row = (lane>>4)*4 + reg
    #pragma unroll
    for (int i = 0; i < 4; ++i)
        #pragma unroll
        for (int j = 0; j < 4; ++j)
            #pragma unroll
            for (int r = 0; r < 4; ++r) {
                int row = mr + i * 16 + (lane >> 4) * 4 + r;
                int col = wc * 64 + j * 16 + (lane & 15);
                if (row < M) C[(size_t)row * N + col] = (_Float16)acc[i][j][r];
            }
    if (wc == 3) {
        int c16 = lane & 15;
        #pragma unroll
        for (int i = 0; i < 4; ++i)
            #pragma unroll
            for (int r = 0; r < 4; ++r) {
                int row = mr + i * 16 + (lane >> 4) * 4 + r;
                if (row < M) {
                    if (c16 < 8) el[row * 8 + c16] = acce[i][r];
                    else         er[row * 8 + (c16 - 8)] = acce[i][r];
                }
            }
    }
}

// ---------- MFMA GEMM, N=32 (layer 2), fused el/er via WLR2 ----------
template <int K>
__global__ __launch_bounds__(256) void k_mfma_gemm32(const _Float16* __restrict__ A,
                                                     const _Float16* __restrict__ BT,
                                                     const _Float16* __restrict__ WLRT,
                                                     _Float16* __restrict__ C,
                                                     float* __restrict__ el,
                                                     float* __restrict__ er, int M) {
    const int N = 32;
    int lane = threadIdx.x & 63, w = threadIdx.x >> 6;
    int mr = blockIdx.x * 256 + w * 64;
    const _Float16* pa[4];
    const _Float16* pb[2];
    #pragma unroll
    for (int t = 0; t < 4; ++t) {
        int row = mr + t * 16 + (lane & 15);
        if (row > M - 1) row = M - 1;
        pa[t] = A + (size_t)row * K + (lane >> 4) * 8;
    }
    #pragma unroll
    for (int t = 0; t < 2; ++t) {
        int col = t * 16 + (lane & 15);
        pb[t] = BT + (size_t)col * K + (lane >> 4) * 8;
    }
    const _Float16* pe = WLRT + (size_t)(lane & 15) * K + (lane >> 4) * 8;
    f32x4 acc[4][2] = {};
    f32x4 acce[4] = {};
    #pragma unroll
    for (int k0 = 0; k0 < K; k0 += 32) {
        f16x8 a[4], b[2], be;
        #pragma unroll
        for (int t = 0; t < 4; ++t) a[t] = *(const f16x8*)(pa[t] + k0);
        #pragma unroll
        for (int t = 0; t < 2; ++t) b[t] = *(const f16x8*)(pb[t] + k0);
        be = *(const f16x8*)(pe + k0);
        #pragma unroll
        for (int i = 0; i < 4; ++i) {
            #pragma unroll
            for (int j = 0; j < 2; ++j)
                acc[i][j] = __builtin_amdgcn_mfma_f32_16x16x32_f16(a[i], b[j], acc[i][j], 0, 0, 0);
            acce[i] = __builtin_amdgcn_mfma_f32_16x16x32_f16(a[i], be, acce[i], 0, 0, 0);
        }
    }
    int c16 = lane & 15;
    #pragma unroll
    for (int i = 0; i < 4; ++i)
        #pragma unroll
        for (int r = 0; r < 4; ++r) {
            int row = mr + i * 16 + (lane >> 4) * 4 + r;
            if (row < M) {
                #pragma unroll
                for (int j = 0; j < 2; ++j)
                    C[(size_t)row * N + j * 16 + c16] = (_Float16)acc[i][j][r];
                if (c16 == 0) el[row] = acce[i][r];
                else if (c16 == 1) er[row] = acce[i][r];
            }
        }
}

// ---------- CSR build ----------
__global__ void k_deg(const int* __restrict__ dst, int* __restrict__ deg, int E) {
    int e = blockIdx.x * blockDim.x + threadIdx.x;
    if (e < E) atomicAdd(deg + dst[e], 1);
}
__global__ __launch_bounds__(256) void k_scan1(const int* __restrict__ deg,
                                               int* __restrict__ bsum, int n) {
    int base = blockIdx.x * 1024;
    int t = threadIdx.x;
    int s = 0;
    #pragma unroll
    for (int i = 0; i < 4; ++i) {
        int idx = base + t * 4 + i;
        if (idx < n) s += deg[idx];
    }
    __shared__ int red[256];
    red[t] = s; __syncthreads();
    for (int off = 128; off; off >>= 1) {
        if (t < off) red[t] += red[t + off];
        __syncthreads();
    }
    if (t == 0) bsum[blockIdx.x] = red[0];
}
// scan3 now also does scan2's job: block offset = sum of bsum[j<blockIdx.x]
__global__ __launch_bounds__(256) void k_scan3(const int* __restrict__ deg,
                                               const int* __restrict__ bsum,
                                               int* __restrict__ row_ptr, int n, int E) {
    int base = blockIdx.x * 1024;
    int t = threadIdx.x;
    __shared__ int boff;
    if (t == 0) {
        int s = 0;
        for (int j = 0; j < blockIdx.x; ++j) s += bsum[j];
        boff = s;
        if (blockIdx.x == 0) row_ptr[n] = E;
    }
    int loc[4]; int s = 0;
    #pragma unroll
    for (int i = 0; i < 4; ++i) {
        int idx = base + t * 4 + i;
        loc[i] = (idx < n) ? deg[idx] : 0;
        s += loc[i];
    }
    __shared__ int part[256];
    part[t] = s; __syncthreads();
    for (int off = 1; off < 256; off <<= 1) {
        int v = (t >= off) ? part[t - off] : 0;
        __syncthreads();
        part[t] += v;
        __syncthreads();
    }
    int run = boff + part[t] - s;
    #pragma unroll
    for (int i = 0; i < 4; ++i) {
        int idx = base + t * 4 + i;
        if (idx < n) row_ptr[idx] = run;
        run += loc[i];
    }
}
__global__ void k_fill(const int* __restrict__ dst, const int* __restrict__ src,
                       const int* __restrict__ row_ptr,
                       int* __restrict__ fill, int* __restrict__ csrc, int E) {
    int e = blockIdx.x * blockDim.x + threadIdx.x;
    if (e < E) {
        int d = dst[e];
        int pos = row_ptr[d] + atomicAdd(fill + d, 1);
        csrc[pos] = src[e];
    }
}

// ---------- fused softmax aggregation, H=8,C=32: single pass, no max ----------
__global__ __launch_bounds__(256) void k_fused256(const int* __restrict__ row_ptr,
                                                  const int* __restrict__ csrc,
                                                  const float* __restrict__ el,
                                                  const float* __restrict__ er,
                                                  const _Float16* __restrict__ ft16,
                                                  const float* __restrict__ b,
                                                  _Float16* __restrict__ out, int n) {
    int wave = threadIdx.x >> 6;
    int lane = threadIdx.x & 63;
    int v = blockIdx.x * 4 + wave;
    if (v >= n) return;
    int g = lane >> 4;            // edge slot 0..3
    int l16 = lane & 15;          // channel group: 16 ch each
    int h = l16 >> 1;             // head (2 lanes per head)
    float erv = er[v * 8 + h];
    const float* elh = el + h;
    int e0 = row_ptr[v], e1 = row_ptr[v + 1];
    float s = 0.f;
    float a[16] = {};
    int k = e0 + g;
    for (; k + 4 < e1; k += 8) {
        int sn0 = csrc[k];
        int sn1 = csrc[k + 4];
        float ev0 = elh[sn0 * 8] + erv;
        float ev1 = elh[sn1 * 8] + erv;
        ev0 = ev0 > 0.f ? ev0 : 0.2f * ev0;
        ev1 = ev1 > 0.f ? ev1 : 0.2f * ev1;
        float w0 = __expf(ev0);
        float w1 = __expf(ev1);
        const _Float16* fp0 = ft16 + (sn0 << 8) + l16 * 16;
        const _Float16* fp1 = ft16 + (sn1 << 8) + l16 * 16;
        f16x8 f00 = *(const f16x8*)fp0;
        f16x8 f01 = *(const f16x8*)(fp0 + 8);
        f16x8 f10 = *(const f16x8*)fp1;
        f16x8 f11 = *(const f16x8*)(fp1 + 8);
        s += w0 + w1;
        #pragma unroll
        for (int j = 0; j < 8; ++j) a[j] += w0 * (float)f00[j];
        #pragma unroll
        for (int j = 0; j < 8; ++j) a[8 + j] += w0 * (float)f01[j];
        #pragma unroll
        for (int j = 0; j < 8; ++j) a[j] += w1 * (float)f10[j];
        #pragma unroll
        for (int j = 0; j < 8; ++j) a[8 + j] += w1 * (float)f11[j];
    }
    if (k < e1) {
        int sn = csrc[k];
        float ev = elh[sn * 8] + erv;
        ev = ev > 0.f ? ev : 0.2f * ev;
        float w = __expf(ev);
        s += w;
        const _Float16* fp = ft16 + (sn << 8) + l16 * 16;
        f16x8 f0 = *(const f16x8*)fp;
        f16x8 f1 = *(const f16x8*)(fp + 8);
        #pragma unroll
        for (int j = 0; j < 8; ++j) a[j] += w * (float)f0[j];
        #pragma unroll
        for (int j = 0; j < 8; ++j) a[8 + j] += w * (float)f1[j];
    }
    s += __shfl_xor(s, 16, 64);
    s += __shfl_xor(s, 32, 64);
    #pragma unroll
    for (int j = 0; j < 16; ++j) {
        a[j] += __shfl_xor(a[j], 16, 64);
        a[j] += __shfl_xor(a[j], 32, 64);
    }
    if (g == 0) {
        float inv = s > 0.f ? 1.f / s : 0.f;
        const float* bp = b + l16 * 16;
        f16x8 o0, o1;
        #pragma unroll
        for (int j = 0; j < 8; ++j) o0[j] = (_Float16)fmaxf(a[j] * inv + bp[j], 0.f);
        #pragma unroll
        for (int j = 0; j < 8; ++j) o1[j] = (_Float16)fmaxf(a[8 + j] * inv + bp[8 + j], 0.f);
        _Float16* op = out + ((size_t)v << 8) + l16 * 16;
        *(f16x8*)op = o0;
        *(f16x8*)(op + 8) = o1;
    }
}

// ---------- fused aggregation, H=1,C=32 (layer 2) + class softmax ----------
__global__ __launch_bounds__(256) void k_fused_out(const int* __restrict__ row_ptr,
                                                   const int* __restrict__ csrc,
                                                   const float* __restrict__ el,
                                                   const float* __restrict__ er,
                                                   const _Float16* __restrict__ ft,
                                                   const float* __restrict__ b,
                                                   float* __restrict__ out, int n) {
    int v = blockIdx.x * 16 + (threadIdx.x >> 4);
    int sub = threadIdx.x & 15;
    int g = sub >> 2;             // edge slot 0..3
    int l4 = sub & 3;             // channel group: 8 ch each
    if (v >= n) return;
    float erv = er[v];
    int e0 = row_ptr[v], e1 = row_ptr[v + 1];
    float s = 0.f;
    float a[8] = {};
    for (int k = e0 + g; k < e1; k += 4) {
        int sn = csrc[k];
        float ev = el[sn] + erv;
        ev = ev > 0.f ? ev : 0.2f * ev;
        float w = __expf(ev);
        s += w;
        f16x8 f = *(const f16x8*)(ft + (sn << 5) + l4 * 8);
        #pragma unroll
        for (int j = 0; j < 8; ++j) a[j] += w * (float)f[j];
    }
    s += __shfl_xor(s, 4, 64);
    s += __shfl_xor(s, 8, 64);
    #pragma unroll
    for (int j = 0; j < 8; ++j) {
        a[j] += __shfl_xor(a[j], 4, 64);
        a[j] += __shfl_xor(a[j], 8, 64);
    }
    float inv = s > 0.f ? 1.f / s : 0.f;
    const float* bp = b + l4 * 8;
    float val[8];
    float mx = -INFINITY;
    #pragma unroll
    for (int j = 0; j < 8; ++j) {
        val[j] = fmaxf(a[j] * inv + bp[j], 0.f);
        mx = fmaxf(mx, val[j]);
    }
    mx = fmaxf(mx, __shfl_xor(mx, 1, 64));
    mx = fmaxf(mx, __shfl_xor(mx, 2, 64));
    float ex[8];
    float sum = 0.f;
    #pragma unroll
    for (int j = 0; j < 8; ++j) { ex[j] = __expf(val[j] - mx); sum += ex[j]; }
    sum += __shfl_xor(sum, 1, 64);
    sum += __shfl_xor(sum, 2, 64);
    float isum = 1.f / sum;
    if (g == 0) {
        float* op = out + ((size_t)v << 5) + l4 * 8;
        *(float4*)op = make_float4(ex[0] * isum, ex[1] * isum, ex[2] * isum, ex[3] * isum);
        *(float4*)(op + 4) = make_float4(ex[4] * isum, ex[5] * isum, ex[6] * isum, ex[7] * isum);
    }
}

extern "C" void kernel_launch(void* const* d_in, const int* in_sizes, int n_in,
                              void* d_out, int out_size, void* d_ws, size_t ws_size,
                              hipStream_t stream) {
    const float* x  = (const float*)d_in[0];
    const int* src  = (const int*)d_in[1];
    const int* dst  = (const int*)d_in[2];
    const float* W0 = (const float*)d_in[3];
    const float* al0 = (const float*)d_in[4];
    const float* ar0 = (const float*)d_in[5];
    const float* b0  = (const float*)d_in[6];
    const float* W1 = (const float*)d_in[7];
    const float* al1 = (const float*)d_in[8];
    const float* ar1 = (const float*)d_in[9];
    const float* b1  = (const float*)d_in[10];
    const float* W2 = (const float*)d_in[11];
    const float* al2 = (const float*)d_in[12];
    const float* ar2 = (const float*)d_in[13];
    const float* b2  = (const float*)d_in[14];
    float* out = (float*)d_out;

    const int n = in_sizes[0] / IN_FEATS;   // 50000
    const int E = in_sizes[1];              // 800000

    // ---- workspace carve (256B-aligned) ----
    char* p = (char*)d_ws;
    auto alloc = [&](size_t bytes) {
        void* r = (void*)p;
        p += (bytes + 255) & ~(size_t)255;
        return r;
    };
    _Float16* ft16  = (_Float16*)alloc((size_t)n * 256 * 2);
    _Float16* h16   = (_Float16*)alloc((size_t)n * 256 * 2);
    _Float16* W0T   = (_Float16*)alloc((size_t)256 * 128 * 2);
    _Float16* W1T   = (_Float16*)alloc((size_t)256 * 256 * 2);
    _Float16* W2T   = (_Float16*)alloc((size_t)32 * 256 * 2);
    _Float16* WLR0  = (_Float16*)alloc((size_t)16 * 128 * 2);
    _Float16* WLR1  = (_Float16*)alloc((size_t)16 * 256 * 2);
    _Float16* WLR2  = (_Float16*)alloc((size_t)16 * 256 * 2);
    float* el       = (float*)alloc((size_t)n * 8 * 4);
    float* er       = (float*)alloc((size_t)n * 8 * 4);
    int* deg        = (int*)alloc((size_t)n * 4);
    int* fill       = (int*)alloc((size_t)n * 4);   // adjacent to deg: one memset
    int* row_ptr    = (int*)alloc((size_t)(n + 1) * 4);
    int* csrc       = (int*)alloc((size_t)E * 4);
    int* bsum       = (int*)alloc((size_t)64 * 4);

    const int EB = (E + 255) / 256;
    const int NBCH = (n + 1023) / 1024;     // 49 scan blocks

    // ---- CSR by dst (one memset covers deg+fill, they are adjacent) ----
    hipMemsetAsync(deg, 0, (size_t)((char*)fill - (char*)deg) + (size_t)n * 4, stream);
    k_deg<<<EB, 256, 0, stream>>>(dst, deg, E);
    k_scan1<<<NBCH, 256, 0, stream>>>(deg, bsum, n);
    k_scan3<<<NBCH, 256, 0, stream>>>(deg, bsum, row_ptr, n, E);
    k_fill<<<EB, 256, 0, stream>>>(dst, src, row_ptr, fill, csrc, E);

    // ---- merged weight prep ----
    k_prep<<<456, 256, 0, stream>>>(W0, W1, W2, al0, ar0, al1, ar1, al2, ar2,
                                    W0T, W1T, W2T, WLR0, WLR1, WLR2);

    const int GB = (n + 63) / 64;
    const int GB32 = (n + 255) / 256;
    const int FB = (n + 3) / 4;
    const int OB = (n + 15) / 16;

    // ---- layer 0 (A = x, fp32, cast in staging) ----
    k_mfma_gemm<128, float><<<GB, 256, 0, stream>>>(x, W0T, WLR0, ft16, el, er, n);
    k_fused256<<<FB, 256, 0, stream>>>(row_ptr, csrc, el, er, ft16, b0, h16, n);

    // ---- layer 1 ----
    k_mfma_gemm<256, _Float16><<<GB, 256, 0, stream>>>(h16, W1T, WLR1, ft16, el, er, n);
    k_fused256<<<FB, 256, 0, stream>>>(row_ptr, csrc, el, er, ft16, b1, h16, n);

    // ---- layer 2 + class softmax ----
    k_mfma_gemm32<256><<<GB32, 256, 0, stream>>>(h16, W2T, WLR2, ft16, el, er, n);
    k_fused_out<<<OB, 256, 0, stream>>>(row_ptr, csrc, el, er, ft16, b2, out, n);
}

// Round 10
// 337.181 us; speedup vs baseline: 1.2179x; 1.1282x over previous
//
#include <hip/hip_runtime.h>
#include <hip/hip_fp16.h>
#include <cstdint>
#include <cstddef>

// GAT 3-layer forward for MI355X — round 10.
// Changes vs round 9 (380us):
//  * Layers 0/1: GEMM output ft is consumed ONLY by the fused256 gather (el/er
//    live in the GEMM now) -> emit it directly as fp8 e4m3 (v_cvt_pk_fp8_f32
//    in the epilogue, v_cvt_f32_fp8 decode in the gather). Halves the gather
//    bytes (512->256 B/row); fused256 was at its fp16 byte ceiling
//    (12.6 B/cy/CU, ILP-flat in round 8). No fp16 ft copy exists anymore.
//  * Layer 2 path (3.2 MB, L2-resident) stays fp16.
//  REVERT PLAN: if absmax fails, round 9 source is the fallback.

#define IN_FEATS 128

typedef _Float16 f16x8 __attribute__((ext_vector_type(8)));
typedef float f32x4 __attribute__((ext_vector_type(4)));

// ---------- fp8 helpers (HW cvt; self-consistent encode/decode on gfx950) ----------
__device__ __forceinline__ unsigned char f32_to_fp8(float f) {
    int p = __builtin_amdgcn_cvt_pk_fp8_f32(f, 0.f, 0, false);
    return (unsigned char)(p & 0xff);
}
__device__ __forceinline__ void fp8x4_to_f32(unsigned w, float* o) {
    o[0] = __builtin_amdgcn_cvt_f32_fp8(w, 0);
    o[1] = __builtin_amdgcn_cvt_f32_fp8(w, 1);
    o[2] = __builtin_amdgcn_cvt_f32_fp8(w, 2);
    o[3] = __builtin_amdgcn_cvt_f32_fp8(w, 3);
}

// ---------- merged weight prep ----------
__global__ __launch_bounds__(256) void k_prep(
    const float* __restrict__ W0, const float* __restrict__ W1, const float* __restrict__ W2,
    const float* __restrict__ al0, const float* __restrict__ ar0,
    const float* __restrict__ al1, const float* __restrict__ ar1,
    const float* __restrict__ al2, const float* __restrict__ ar2,
    _Float16* __restrict__ W0T, _Float16* __restrict__ W1T, _Float16* __restrict__ W2T,
    _Float16* __restrict__ WLR0, _Float16* __restrict__ WLR1, _Float16* __restrict__ WLR2) {
    int bid = blockIdx.x, t = threadIdx.x;
    if (bid < 128) {                       // W0T [256][128]
        int i = bid * 256 + t;
        int nn = i >> 7, kk = i & 127;
        W0T[i] = (_Float16)W0[(size_t)kk * 256 + nn];
    } else if (bid < 384) {                // W1T [256][256]
        int i = (bid - 128) * 256 + t;
        int nn = i >> 8, kk = i & 255;
        W1T[i] = (_Float16)W1[(size_t)kk * 256 + nn];
    } else if (bid < 416) {                // W2T [32][256]
        int i = (bid - 384) * 256 + t;
        int nn = i >> 8, kk = i & 255;
        W2T[i] = (_Float16)W2[(size_t)kk * 32 + nn];
    } else if (bid < 424) {                // WLR0 [16][128]
        int i = (bid - 416) * 256 + t;
        int j = i >> 7, k = i & 127;
        int h = j & 7;
        const float* av = (j < 8) ? al0 : ar0;
        float sum = 0.f;
        #pragma unroll 8
        for (int c = 0; c < 32; ++c) sum += W0[(size_t)k * 256 + h * 32 + c] * av[h * 32 + c];
        WLR0[i] = (_Float16)sum;
    } else if (bid < 440) {                // WLR1 [16][256]
        int i = (bid - 424) * 256 + t;
        int j = i >> 8, k = i & 255;
        int h = j & 7;
        const float* av = (j < 8) ? al1 : ar1;
        float sum = 0.f;
        #pragma unroll 8
        for (int c = 0; c < 32; ++c) sum += W1[(size_t)k * 256 + h * 32 + c] * av[h * 32 + c];
        WLR1[i] = (_Float16)sum;
    } else {                               // WLR2 [16][256]
        int i = (bid - 440) * 256 + t;
        int j = i >> 8, k = i & 255;
        float sum = 0.f;
        if (j < 2) {
            const float* av = (j == 0) ? al2 : ar2;
            #pragma unroll 8
            for (int c = 0; c < 32; ++c) sum += W2[(size_t)k * 32 + c] * av[c];
        }
        WLR2[i] = (_Float16)sum;
    }
}

// ---------- MFMA GEMM, N=256, A via LDS; C out in fp8; wave 3 emits el/er ----------
template <int K, typename AT>
__global__ __launch_bounds__(256) void k_mfma_gemm(const AT* __restrict__ A,
                                                   const _Float16* __restrict__ BT,
                                                   const _Float16* __restrict__ WLRT,
                                                   unsigned char* __restrict__ C8,
                                                   float* __restrict__ el,
                                                   float* __restrict__ er, int M) {
    const int N = 256;
    const int LDA = K + 8;
    __shared__ _Float16 As[64 * LDA];
    int tid = threadIdx.x;
    int lane = tid & 63, wc = tid >> 6;
    int mr = blockIdx.x * 64;
    #pragma unroll
    for (int it = 0; it < K / 32; ++it) {
        int idx = (it * 256 + tid) * 8;
        int row = idx / K, col = idx % K;
        int rowg = mr + row; if (rowg > M - 1) rowg = M - 1;
        f16x8 v;
        if constexpr (sizeof(AT) == 2) {
            v = *(const f16x8*)(A + (size_t)rowg * K + col);
        } else {
            float4 u0 = *(const float4*)(A + (size_t)rowg * K + col);
            float4 u1 = *(const float4*)(A + (size_t)rowg * K + col + 4);
            v[0] = (_Float16)u0.x; v[1] = (_Float16)u0.y;
            v[2] = (_Float16)u0.z; v[3] = (_Float16)u0.w;
            v[4] = (_Float16)u1.x; v[5] = (_Float16)u1.y;
            v[6] = (_Float16)u1.z; v[7] = (_Float16)u1.w;
        }
        *(f16x8*)(As + row * LDA + col) = v;
    }
    __syncthreads();
    const _Float16* pb[4];
    #pragma unroll
    for (int j = 0; j < 4; ++j) {
        int col = wc * 64 + j * 16 + (lane & 15);
        pb[j] = BT + (size_t)col * K + (lane >> 4) * 8;
    }
    const _Float16* pe = WLRT + (size_t)(lane & 15) * K + (lane >> 4) * 8;
    const _Float16* pa = As + (lane & 15) * LDA + (lane >> 4) * 8;
    f32x4 acc[4][4] = {};
    f32x4 acce[4] = {};
    #pragma unroll
    for (int k0 = 0; k0 < K; k0 += 32) {
        f16x8 a[4], b[4];
        #pragma unroll
        for (int t = 0; t < 4; ++t) a[t] = *(const f16x8*)(pa + t * 16 * LDA + k0);
        #pragma unroll
        for (int t = 0; t < 4; ++t) b[t] = *(const f16x8*)(pb[t] + k0);
        #pragma unroll
        for (int i = 0; i < 4; ++i)
            #pragma unroll
            for (int j = 0; j < 4; ++j)
                acc[i][j] = __builtin_amdgcn_mfma_f32_16x16x32_f16(a[i], b[j], acc[i][j], 0, 0, 0);
        if (wc == 3) {
            f16x8 be = *(const f16x8*)(pe + k0);
            #pragma unroll
            for (int i = 0; i < 4; ++i)
                acce[i] = __builtin_amdgcn_mfma_f32_16x16x32_f16(a[i], be, acce[i], 0, 0, 0);
        }
    }
    // C/D layout: col = lane&15, row = (lane>>4)*4 + reg
    #pragma unroll
    for (int i = 0; i < 4; ++i)
        #pragma unroll
        for (int j = 0; j < 4; ++j)
            #pragma unroll
            for (int r = 0; r < 4; ++r) {
                int row = mr + i * 16 + (lane >> 4) * 4 + r;
                int col = wc * 64 + j * 16 + (lane & 15);
                if (row < M) C8[(size_t)row * N + col] = f32_to_fp8(acc[i][j][r]);
            }
    if (wc == 3) {
        int c16 = lane & 15;
        #pragma unroll
        for (int i = 0; i < 4; ++i)
            #pragma unroll
            for (int r = 0; r < 4; ++r) {
                int row = mr + i * 16 + (lane >> 4) * 4 + r;
                if (row < M) {
                    if (c16 < 8) el[row * 8 + c16] = acce[i][r];
                    else         er[row * 8 + (c16 - 8)] = acce[i][r];
                }
            }
    }
}

// ---------- MFMA GEMM, N=32 (layer 2), fp16 out, fused el/er via WLR2 ----------
template <int K>
__global__ __launch_bounds__(256) void k_mfma_gemm32(const _Float16* __restrict__ A,
                                                     const _Float16* __restrict__ BT,
                                                     const _Float16* __restrict__ WLRT,
                                                     _Float16* __restrict__ C,
                                                     float* __restrict__ el,
                                                     float* __restrict__ er, int M) {
    const int N = 32;
    int lane = threadIdx.x & 63, w = threadIdx.x >> 6;
    int mr = blockIdx.x * 256 + w * 64;
    const _Float16* pa[4];
    const _Float16* pb[2];
    #pragma unroll
    for (int t = 0; t < 4; ++t) {
        int row = mr + t * 16 + (lane & 15);
        if (row > M - 1) row = M - 1;
        pa[t] = A + (size_t)row * K + (lane >> 4) * 8;
    }
    #pragma unroll
    for (int t = 0; t < 2; ++t) {
        int col = t * 16 + (lane & 15);
        pb[t] = BT + (size_t)col * K + (lane >> 4) * 8;
    }
    const _Float16* pe = WLRT + (size_t)(lane & 15) * K + (lane >> 4) * 8;
    f32x4 acc[4][2] = {};
    f32x4 acce[4] = {};
    #pragma unroll
    for (int k0 = 0; k0 < K; k0 += 32) {
        f16x8 a[4], b[2], be;
        #pragma unroll
        for (int t = 0; t < 4; ++t) a[t] = *(const f16x8*)(pa[t] + k0);
        #pragma unroll
        for (int t = 0; t < 2; ++t) b[t] = *(const f16x8*)(pb[t] + k0);
        be = *(const f16x8*)(pe + k0);
        #pragma unroll
        for (int i = 0; i < 4; ++i) {
            #pragma unroll
            for (int j = 0; j < 2; ++j)
                acc[i][j] = __builtin_amdgcn_mfma_f32_16x16x32_f16(a[i], b[j], acc[i][j], 0, 0, 0);
            acce[i] = __builtin_amdgcn_mfma_f32_16x16x32_f16(a[i], be, acce[i], 0, 0, 0);
        }
    }
    int c16 = lane & 15;
    #pragma unroll
    for (int i = 0; i < 4; ++i)
        #pragma unroll
        for (int r = 0; r < 4; ++r) {
            int row = mr + i * 16 + (lane >> 4) * 4 + r;
            if (row < M) {
                #pragma unroll
                for (int j = 0; j < 2; ++j)
                    C[(size_t)row * N + j * 16 + c16] = (_Float16)acc[i][j][r];
                if (c16 == 0) el[row] = acce[i][r];
                else if (c16 == 1) er[row] = acce[i][r];
            }
        }
}

// ---------- CSR build ----------
__global__ void k_deg(const int* __restrict__ dst, int* __restrict__ deg, int E) {
    int e = blockIdx.x * blockDim.x + threadIdx.x;
    if (e < E) atomicAdd(deg + dst[e], 1);
}
__global__ __launch_bounds__(256) void k_scan1(const int* __restrict__ deg,
                                               int* __restrict__ bsum, int n) {
    int base = blockIdx.x * 1024;
    int t = threadIdx.x;
    int s = 0;
    #pragma unroll
    for (int i = 0; i < 4; ++i) {
        int idx = base + t * 4 + i;
        if (idx < n) s += deg[idx];
    }
    __shared__ int red[256];
    red[t] = s; __syncthreads();
    for (int off = 128; off; off >>= 1) {
        if (t < off) red[t] += red[t + off];
        __syncthreads();
    }
    if (t == 0) bsum[blockIdx.x] = red[0];
}
__global__ __launch_bounds__(256) void k_scan3(const int* __restrict__ deg,
                                               const int* __restrict__ bsum,
                                               int* __restrict__ row_ptr, int n, int E) {
    int base = blockIdx.x * 1024;
    int t = threadIdx.x;
    __shared__ int boff;
    if (t == 0) {
        int s = 0;
        for (int j = 0; j < blockIdx.x; ++j) s += bsum[j];
        boff = s;
        if (blockIdx.x == 0) row_ptr[n] = E;
    }
    int loc[4]; int s = 0;
    #pragma unroll
    for (int i = 0; i < 4; ++i) {
        int idx = base + t * 4 + i;
        loc[i] = (idx < n) ? deg[idx] : 0;
        s += loc[i];
    }
    __shared__ int part[256];
    part[t] = s; __syncthreads();
    for (int off = 1; off < 256; off <<= 1) {
        int v = (t >= off) ? part[t - off] : 0;
        __syncthreads();
        part[t] += v;
        __syncthreads();
    }
    int run = boff + part[t] - s;
    #pragma unroll
    for (int i = 0; i < 4; ++i) {
        int idx = base + t * 4 + i;
        if (idx < n) row_ptr[idx] = run;
        run += loc[i];
    }
}
__global__ void k_fill(const int* __restrict__ dst, const int* __restrict__ src,
                       const int* __restrict__ row_ptr,
                       int* __restrict__ fill, int* __restrict__ csrc, int E) {
    int e = blockIdx.x * blockDim.x + threadIdx.x;
    if (e < E) {
        int d = dst[e];
        int pos = row_ptr[d] + atomicAdd(fill + d, 1);
        csrc[pos] = src[e];
    }
}

// ---------- fused softmax aggregation, H=8,C=32: single pass, fp8 gather ----------
// One wave per node; 4 edge slots x 16 lanes; lane covers 16 channels (16B fp8);
// unroll x2 -> 8 gathers in flight.
__global__ __launch_bounds__(256) void k_fused256(const int* __restrict__ row_ptr,
                                                  const int* __restrict__ csrc,
                                                  const float* __restrict__ el,
                                                  const float* __restrict__ er,
                                                  const unsigned char* __restrict__ ft8,
                                                  const float* __restrict__ b,
                                                  _Float16* __restrict__ out, int n) {
    int wave = threadIdx.x >> 6;
    int lane = threadIdx.x & 63;
    int v = blockIdx.x * 4 + wave;
    if (v >= n) return;
    int g = lane >> 4;            // edge slot 0..3
    int l16 = lane & 15;          // channel group: 16 ch each
    int h = l16 >> 1;             // head (2 lanes per head)
    float erv = er[v * 8 + h];
    const float* elh = el + h;
    int e0 = row_ptr[v], e1 = row_ptr[v + 1];
    float s = 0.f;
    float a[16] = {};
    int k = e0 + g;
    for (; k + 4 < e1; k += 8) {
        int sn0 = csrc[k];
        int sn1 = csrc[k + 4];
        float ev0 = elh[sn0 * 8] + erv;
        float ev1 = elh[sn1 * 8] + erv;
        ev0 = ev0 > 0.f ? ev0 : 0.2f * ev0;
        ev1 = ev1 > 0.f ? ev1 : 0.2f * ev1;
        float w0 = __expf(ev0);
        float w1 = __expf(ev1);
        uint4 q0 = *(const uint4*)(ft8 + ((size_t)sn0 << 8) + l16 * 16);
        uint4 q1 = *(const uint4*)(ft8 + ((size_t)sn1 << 8) + l16 * 16);
        float f0[16], f1[16];
        fp8x4_to_f32(q0.x, f0);     fp8x4_to_f32(q0.y, f0 + 4);
        fp8x4_to_f32(q0.z, f0 + 8); fp8x4_to_f32(q0.w, f0 + 12);
        fp8x4_to_f32(q1.x, f1);     fp8x4_to_f32(q1.y, f1 + 4);
        fp8x4_to_f32(q1.z, f1 + 8); fp8x4_to_f32(q1.w, f1 + 12);
        s += w0 + w1;
        #pragma unroll
        for (int j = 0; j < 16; ++j) a[j] += w0 * f0[j];
        #pragma unroll
        for (int j = 0; j < 16; ++j) a[j] += w1 * f1[j];
    }
    if (k < e1) {
        int sn = csrc[k];
        float ev = elh[sn * 8] + erv;
        ev = ev > 0.f ? ev : 0.2f * ev;
        float w = __expf(ev);
        s += w;
        uint4 q = *(const uint4*)(ft8 + ((size_t)sn << 8) + l16 * 16);
        float f[16];
        fp8x4_to_f32(q.x, f);     fp8x4_to_f32(q.y, f + 4);
        fp8x4_to_f32(q.z, f + 8); fp8x4_to_f32(q.w, f + 12);
        #pragma unroll
        for (int j = 0; j < 16; ++j) a[j] += w * f[j];
    }
    s += __shfl_xor(s, 16, 64);
    s += __shfl_xor(s, 32, 64);
    #pragma unroll
    for (int j = 0; j < 16; ++j) {
        a[j] += __shfl_xor(a[j], 16, 64);
        a[j] += __shfl_xor(a[j], 32, 64);
    }
    if (g == 0) {
        float inv = s > 0.f ? 1.f / s : 0.f;
        const float* bp = b + l16 * 16;
        f16x8 o0, o1;
        #pragma unroll
        for (int j = 0; j < 8; ++j) o0[j] = (_Float16)fmaxf(a[j] * inv + bp[j], 0.f);
        #pragma unroll
        for (int j = 0; j < 8; ++j) o1[j] = (_Float16)fmaxf(a[8 + j] * inv + bp[8 + j], 0.f);
        _Float16* op = out + ((size_t)v << 8) + l16 * 16;
        *(f16x8*)op = o0;
        *(f16x8*)(op + 8) = o1;
    }
}

// ---------- fused aggregation, H=1,C=32 (layer 2) + class softmax (fp16 ft) ----------
__global__ __launch_bounds__(256) void k_fused_out(const int* __restrict__ row_ptr,
                                                   const int* __restrict__ csrc,
                                                   const float* __restrict__ el,
                                                   const float* __restrict__ er,
                                                   const _Float16* __restrict__ ft,
                                                   const float* __restrict__ b,
                                                   float* __restrict__ out, int n) {
    int v = blockIdx.x * 16 + (threadIdx.x >> 4);
    int sub = threadIdx.x & 15;
    int g = sub >> 2;             // edge slot 0..3
    int l4 = sub & 3;             // channel group: 8 ch each
    if (v >= n) return;
    float erv = er[v];
    int e0 = row_ptr[v], e1 = row_ptr[v + 1];
    float s = 0.f;
    float a[8] = {};
    for (int k = e0 + g; k < e1; k += 4) {
        int sn = csrc[k];
        float ev = el[sn] + erv;
        ev = ev > 0.f ? ev : 0.2f * ev;
        float w = __expf(ev);
        s += w;
        f16x8 f = *(const f16x8*)(ft + (sn << 5) + l4 * 8);
        #pragma unroll
        for (int j = 0; j < 8; ++j) a[j] += w * (float)f[j];
    }
    s += __shfl_xor(s, 4, 64);
    s += __shfl_xor(s, 8, 64);
    #pragma unroll
    for (int j = 0; j < 8; ++j) {
        a[j] += __shfl_xor(a[j], 4, 64);
        a[j] += __shfl_xor(a[j], 8, 64);
    }
    float inv = s > 0.f ? 1.f / s : 0.f;
    const float* bp = b + l4 * 8;
    float val[8];
    float mx = -INFINITY;
    #pragma unroll
    for (int j = 0; j < 8; ++j) {
        val[j] = fmaxf(a[j] * inv + bp[j], 0.f);
        mx = fmaxf(mx, val[j]);
    }
    mx = fmaxf(mx, __shfl_xor(mx, 1, 64));
    mx = fmaxf(mx, __shfl_xor(mx, 2, 64));
    float ex[8];
    float sum = 0.f;
    #pragma unroll
    for (int j = 0; j < 8; ++j) { ex[j] = __expf(val[j] - mx); sum += ex[j]; }
    sum += __shfl_xor(sum, 1, 64);
    sum += __shfl_xor(sum, 2, 64);
    float isum = 1.f / sum;
    if (g == 0) {
        float* op = out + ((size_t)v << 5) + l4 * 8;
        *(float4*)op = make_float4(ex[0] * isum, ex[1] * isum, ex[2] * isum, ex[3] * isum);
        *(float4*)(op + 4) = make_float4(ex[4] * isum, ex[5] * isum, ex[6] * isum, ex[7] * isum);
    }
}

extern "C" void kernel_launch(void* const* d_in, const int* in_sizes, int n_in,
                              void* d_out, int out_size, void* d_ws, size_t ws_size,
                              hipStream_t stream) {
    const float* x  = (const float*)d_in[0];
    const int* src  = (const int*)d_in[1];
    const int* dst  = (const int*)d_in[2];
    const float* W0 = (const float*)d_in[3];
    const float* al0 = (const float*)d_in[4];
    const float* ar0 = (const float*)d_in[5];
    const float* b0  = (const float*)d_in[6];
    const float* W1 = (const float*)d_in[7];
    const float* al1 = (const float*)d_in[8];
    const float* ar1 = (const float*)d_in[9];
    const float* b1  = (const float*)d_in[10];
    const float* W2 = (const float*)d_in[11];
    const float* al2 = (const float*)d_in[12];
    const float* ar2 = (const float*)d_in[13];
    const float* b2  = (const float*)d_in[14];
    float* out = (float*)d_out;

    const int n = in_sizes[0] / IN_FEATS;   // 50000
    const int E = in_sizes[1];              // 800000

    // ---- workspace carve (256B-aligned) ----
    char* p = (char*)d_ws;
    auto alloc = [&](size_t bytes) {
        void* r = (void*)p;
        p += (bytes + 255) & ~(size_t)255;
        return r;
    };
    unsigned char* ft8 = (unsigned char*)alloc((size_t)n * 256);   // GEMM out (fp8)
    _Float16* h16   = (_Float16*)alloc((size_t)n * 256 * 2);       // agg out
    _Float16* ft16  = (_Float16*)alloc((size_t)n * 32 * 2);        // layer-2 GEMM out
    _Float16* W0T   = (_Float16*)alloc((size_t)256 * 128 * 2);
    _Float16* W1T   = (_Float16*)alloc((size_t)256 * 256 * 2);
    _Float16* W2T   = (_Float16*)alloc((size_t)32 * 256 * 2);
    _Float16* WLR0  = (_Float16*)alloc((size_t)16 * 128 * 2);
    _Float16* WLR1  = (_Float16*)alloc((size_t)16 * 256 * 2);
    _Float16* WLR2  = (_Float16*)alloc((size_t)16 * 256 * 2);
    float* el       = (float*)alloc((size_t)n * 8 * 4);
    float* er       = (float*)alloc((size_t)n * 8 * 4);
    int* deg        = (int*)alloc((size_t)n * 4);
    int* fill       = (int*)alloc((size_t)n * 4);   // adjacent to deg: one memset
    int* row_ptr    = (int*)alloc((size_t)(n + 1) * 4);
    int* csrc       = (int*)alloc((size_t)E * 4);
    int* bsum       = (int*)alloc((size_t)64 * 4);

    const int EB = (E + 255) / 256;
    const int NBCH = (n + 1023) / 1024;     // 49 scan blocks

    // ---- CSR by dst ----
    hipMemsetAsync(deg, 0, (size_t)((char*)fill - (char*)deg) + (size_t)n * 4, stream);
    k_deg<<<EB, 256, 0, stream>>>(dst, deg, E);
    k_scan1<<<NBCH, 256, 0, stream>>>(deg, bsum, n);
    k_scan3<<<NBCH, 256, 0, stream>>>(deg, bsum, row_ptr, n, E);
    k_fill<<<EB, 256, 0, stream>>>(dst, src, row_ptr, fill, csrc, E);

    // ---- merged weight prep ----
    k_prep<<<456, 256, 0, stream>>>(W0, W1, W2, al0, ar0, al1, ar1, al2, ar2,
                                    W0T, W1T, W2T, WLR0, WLR1, WLR2);

    const int GB = (n + 63) / 64;
    const int GB32 = (n + 255) / 256;
    const int FB = (n + 3) / 4;
    const int OB = (n + 15) / 16;

    // ---- layer 0 (A = x, fp32, cast in staging) ----
    k_mfma_gemm<128, float><<<GB, 256, 0, stream>>>(x, W0T, WLR0, ft8, el, er, n);
    k_fused256<<<FB, 256, 0, stream>>>(row_ptr, csrc, el, er, ft8, b0, h16, n);

    // ---- layer 1 ----
    k_mfma_gemm<256, _Float16><<<GB, 256, 0, stream>>>(h16, W1T, WLR1, ft8, el, er, n);
    k_fused256<<<FB, 256, 0, stream>>>(row_ptr, csrc, el, er, ft8, b1, h16, n);

    // ---- layer 2 + class softmax ----
    k_mfma_gemm32<256><<<GB32, 256, 0, stream>>>(h16, W2T, WLR2, ft16, el, er, n);
    k_fused_out<<<OB, 256, 0, stream>>>(row_ptr, csrc, el, er, ft16, b2, out, n);
}

// Round 11
// 323.115 us; speedup vs baseline: 1.2709x; 1.0435x over previous
//
#include <hip/hip_runtime.h>
#include <hip/hip_fp16.h>
#include <cstdint>
#include <cstddef>

// GAT 3-layer forward for MI355X — round 11.
// Changes vs round 10 (337us):
//  * k_fill (50us, latency-bound scatter: VALU 0.5%, HBM 15%) fused with the
//    layer-0 GEMM via blockIdx-range split — independent dep chains overlap
//    on-CU (fill waits on memory while GEMM waves use MFMA).
//  * k_deg fused with k_prep the same way.
//  * k_fused256: unroll 4 (4 gather chains issued before decode/FMA) — fp8
//    halved the bytes, so the kernel may be latency-bound again. Flat => fp8
//    byte ceiling confirmed, kernel done.

#define IN_FEATS 128

typedef _Float16 f16x8 __attribute__((ext_vector_type(8)));
typedef float f32x4 __attribute__((ext_vector_type(4)));

// ---------- fp8 helpers (HW cvt; self-consistent encode/decode) ----------
__device__ __forceinline__ unsigned char f32_to_fp8(float f) {
    int p = __builtin_amdgcn_cvt_pk_fp8_f32(f, 0.f, 0, false);
    return (unsigned char)(p & 0xff);
}
__device__ __forceinline__ void fp8x4_to_f32(unsigned w, float* o) {
    o[0] = __builtin_amdgcn_cvt_f32_fp8(w, 0);
    o[1] = __builtin_amdgcn_cvt_f32_fp8(w, 1);
    o[2] = __builtin_amdgcn_cvt_f32_fp8(w, 2);
    o[3] = __builtin_amdgcn_cvt_f32_fp8(w, 3);
}

// ---------- fused: weight prep (blocks 0..455) ∥ degree count (rest) ----------
__global__ __launch_bounds__(256) void k_degprep(
    const float* __restrict__ W0, const float* __restrict__ W1, const float* __restrict__ W2,
    const float* __restrict__ al0, const float* __restrict__ ar0,
    const float* __restrict__ al1, const float* __restrict__ ar1,
    const float* __restrict__ al2, const float* __restrict__ ar2,
    _Float16* __restrict__ W0T, _Float16* __restrict__ W1T, _Float16* __restrict__ W2T,
    _Float16* __restrict__ WLR0, _Float16* __restrict__ WLR1, _Float16* __restrict__ WLR2,
    const int* __restrict__ dst, int* __restrict__ deg, int E) {
    int bid = blockIdx.x, t = threadIdx.x;
    if (bid >= 456) {                      // degree count
        int e = (bid - 456) * 256 + t;
        if (e < E) atomicAdd(deg + dst[e], 1);
        return;
    }
    if (bid < 128) {                       // W0T [256][128]
        int i = bid * 256 + t;
        int nn = i >> 7, kk = i & 127;
        W0T[i] = (_Float16)W0[(size_t)kk * 256 + nn];
    } else if (bid < 384) {                // W1T [256][256]
        int i = (bid - 128) * 256 + t;
        int nn = i >> 8, kk = i & 255;
        W1T[i] = (_Float16)W1[(size_t)kk * 256 + nn];
    } else if (bid < 416) {                // W2T [32][256]
        int i = (bid - 384) * 256 + t;
        int nn = i >> 8, kk = i & 255;
        W2T[i] = (_Float16)W2[(size_t)kk * 32 + nn];
    } else if (bid < 424) {                // WLR0 [16][128]
        int i = (bid - 416) * 256 + t;
        int j = i >> 7, k = i & 127;
        int h = j & 7;
        const float* av = (j < 8) ? al0 : ar0;
        float sum = 0.f;
        #pragma unroll 8
        for (int c = 0; c < 32; ++c) sum += W0[(size_t)k * 256 + h * 32 + c] * av[h * 32 + c];
        WLR0[i] = (_Float16)sum;
    } else if (bid < 440) {                // WLR1 [16][256]
        int i = (bid - 424) * 256 + t;
        int j = i >> 8, k = i & 255;
        int h = j & 7;
        const float* av = (j < 8) ? al1 : ar1;
        float sum = 0.f;
        #pragma unroll 8
        for (int c = 0; c < 32; ++c) sum += W1[(size_t)k * 256 + h * 32 + c] * av[h * 32 + c];
        WLR1[i] = (_Float16)sum;
    } else if (bid < 456) {                // WLR2 [16][256]
        int i = (bid - 440) * 256 + t;
        int j = i >> 8, k = i & 255;
        float sum = 0.f;
        if (j < 2) {
            const float* av = (j == 0) ? al2 : ar2;
            #pragma unroll 8
            for (int c = 0; c < 32; ++c) sum += W2[(size_t)k * 32 + c] * av[c];
        }
        WLR2[i] = (_Float16)sum;
    }
}

// ---------- fused: layer-0 GEMM (blocks < GB) ∥ CSR fill (rest) ----------
// GEMM: C8[M,256] = cast_fp8(A[M,128] @ W0T^T); wave 3 emits el/er via WLR.
__global__ __launch_bounds__(256) void k_gemm0_fill(
    const float* __restrict__ A, const _Float16* __restrict__ BT,
    const _Float16* __restrict__ WLRT, unsigned char* __restrict__ C8,
    float* __restrict__ el, float* __restrict__ er, int M, int GB,
    const int* __restrict__ dst, const int* __restrict__ src,
    const int* __restrict__ row_ptr, int* __restrict__ fill,
    int* __restrict__ csrc, int E) {
    const int K = 128, N = 256, LDA = K + 8;
    __shared__ _Float16 As[64 * LDA];
    int tid = threadIdx.x;
    if ((int)blockIdx.x >= GB) {           // ---- fill branch ----
        int e = ((int)blockIdx.x - GB) * 256 + tid;
        if (e < E) {
            int d = dst[e];
            int pos = row_ptr[d] + atomicAdd(fill + d, 1);
            csrc[pos] = src[e];
        }
        return;
    }
    // ---- GEMM branch (K=128, A fp32 cast in staging) ----
    int lane = tid & 63, wc = tid >> 6;
    int mr = blockIdx.x * 64;
    #pragma unroll
    for (int it = 0; it < K / 32; ++it) {
        int idx = (it * 256 + tid) * 8;
        int row = idx / K, col = idx % K;
        int rowg = mr + row; if (rowg > M - 1) rowg = M - 1;
        float4 u0 = *(const float4*)(A + (size_t)rowg * K + col);
        float4 u1 = *(const float4*)(A + (size_t)rowg * K + col + 4);
        f16x8 v;
        v[0] = (_Float16)u0.x; v[1] = (_Float16)u0.y;
        v[2] = (_Float16)u0.z; v[3] = (_Float16)u0.w;
        v[4] = (_Float16)u1.x; v[5] = (_Float16)u1.y;
        v[6] = (_Float16)u1.z; v[7] = (_Float16)u1.w;
        *(f16x8*)(As + row * LDA + col) = v;
    }
    __syncthreads();
    const _Float16* pb[4];
    #pragma unroll
    for (int j = 0; j < 4; ++j) {
        int col = wc * 64 + j * 16 + (lane & 15);
        pb[j] = BT + (size_t)col * K + (lane >> 4) * 8;
    }
    const _Float16* pe = WLRT + (size_t)(lane & 15) * K + (lane >> 4) * 8;
    const _Float16* pa = As + (lane & 15) * LDA + (lane >> 4) * 8;
    f32x4 acc[4][4] = {};
    f32x4 acce[4] = {};
    #pragma unroll
    for (int k0 = 0; k0 < K; k0 += 32) {
        f16x8 a[4], b[4];
        #pragma unroll
        for (int t = 0; t < 4; ++t) a[t] = *(const f16x8*)(pa + t * 16 * LDA + k0);
        #pragma unroll
        for (int t = 0; t < 4; ++t) b[t] = *(const f16x8*)(pb[t] + k0);
        #pragma unroll
        for (int i = 0; i < 4; ++i)
            #pragma unroll
            for (int j = 0; j < 4; ++j)
                acc[i][j] = __builtin_amdgcn_mfma_f32_16x16x32_f16(a[i], b[j], acc[i][j], 0, 0, 0);
        if (wc == 3) {
            f16x8 be = *(const f16x8*)(pe + k0);
            #pragma unroll
            for (int i = 0; i < 4; ++i)
                acce[i] = __builtin_amdgcn_mfma_f32_16x16x32_f16(a[i], be, acce[i], 0, 0, 0);
        }
    }
    #pragma unroll
    for (int i = 0; i < 4; ++i)
        #pragma unroll
        for (int j = 0; j < 4; ++j)
            #pragma unroll
            for (int r = 0; r < 4; ++r) {
                int row = mr + i * 16 + (lane >> 4) * 4 + r;
                int col = wc * 64 + j * 16 + (lane & 15);
                if (row < M) C8[(size_t)row * N + col] = f32_to_fp8(acc[i][j][r]);
            }
    if (wc == 3) {
        int c16 = lane & 15;
        #pragma unroll
        for (int i = 0; i < 4; ++i)
            #pragma unroll
            for (int r = 0; r < 4; ++r) {
                int row = mr + i * 16 + (lane >> 4) * 4 + r;
                if (row < M) {
                    if (c16 < 8) el[row * 8 + c16] = acce[i][r];
                    else         er[row * 8 + (c16 - 8)] = acce[i][r];
                }
            }
    }
}

// ---------- MFMA GEMM, N=256 (layer 1), fp16 A, fp8 out; wave 3 emits el/er ----------
template <int K>
__global__ __launch_bounds__(256) void k_mfma_gemm(const _Float16* __restrict__ A,
                                                   const _Float16* __restrict__ BT,
                                                   const _Float16* __restrict__ WLRT,
                                                   unsigned char* __restrict__ C8,
                                                   float* __restrict__ el,
                                                   float* __restrict__ er, int M) {
    const int N = 256;
    const int LDA = K + 8;
    __shared__ _Float16 As[64 * LDA];
    int tid = threadIdx.x;
    int lane = tid & 63, wc = tid >> 6;
    int mr = blockIdx.x * 64;
    #pragma unroll
    for (int it = 0; it < K / 32; ++it) {
        int idx = (it * 256 + tid) * 8;
        int row = idx / K, col = idx % K;
        int rowg = mr + row; if (rowg > M - 1) rowg = M - 1;
        f16x8 v = *(const f16x8*)(A + (size_t)rowg * K + col);
        *(f16x8*)(As + row * LDA + col) = v;
    }
    __syncthreads();
    const _Float16* pb[4];
    #pragma unroll
    for (int j = 0; j < 4; ++j) {
        int col = wc * 64 + j * 16 + (lane & 15);
        pb[j] = BT + (size_t)col * K + (lane >> 4) * 8;
    }
    const _Float16* pe = WLRT + (size_t)(lane & 15) * K + (lane >> 4) * 8;
    const _Float16* pa = As + (lane & 15) * LDA + (lane >> 4) * 8;
    f32x4 acc[4][4] = {};
    f32x4 acce[4] = {};
    #pragma unroll
    for (int k0 = 0; k0 < K; k0 += 32) {
        f16x8 a[4], b[4];
        #pragma unroll
        for (int t = 0; t < 4; ++t) a[t] = *(const f16x8*)(pa + t * 16 * LDA + k0);
        #pragma unroll
        for (int t = 0; t < 4; ++t) b[t] = *(const f16x8*)(pb[t] + k0);
        #pragma unroll
        for (int i = 0; i < 4; ++i)
            #pragma unroll
            for (int j = 0; j < 4; ++j)
                acc[i][j] = __builtin_amdgcn_mfma_f32_16x16x32_f16(a[i], b[j], acc[i][j], 0, 0, 0);
        if (wc == 3) {
            f16x8 be = *(const f16x8*)(pe + k0);
            #pragma unroll
            for (int i = 0; i < 4; ++i)
                acce[i] = __builtin_amdgcn_mfma_f32_16x16x32_f16(a[i], be, acce[i], 0, 0, 0);
        }
    }
    #pragma unroll
    for (int i = 0; i < 4; ++i)
        #pragma unroll
        for (int j = 0; j < 4; ++j)
            #pragma unroll
            for (int r = 0; r < 4; ++r) {
                int row = mr + i * 16 + (lane >> 4) * 4 + r;
                int col = wc * 64 + j * 16 + (lane & 15);
                if (row < M) C8[(size_t)row * N + col] = f32_to_fp8(acc[i][j][r]);
            }
    if (wc == 3) {
        int c16 = lane & 15;
        #pragma unroll
        for (int i = 0; i < 4; ++i)
            #pragma unroll
            for (int r = 0; r < 4; ++r) {
                int row = mr + i * 16 + (lane >> 4) * 4 + r;
                if (row < M) {
                    if (c16 < 8) el[row * 8 + c16] = acce[i][r];
                    else         er[row * 8 + (c16 - 8)] = acce[i][r];
                }
            }
    }
}

// ---------- MFMA GEMM, N=32 (layer 2), fp16 out, fused el/er via WLR2 ----------
template <int K>
__global__ __launch_bounds__(256) void k_mfma_gemm32(const _Float16* __restrict__ A,
                                                     const _Float16* __restrict__ BT,
                                                     const _Float16* __restrict__ WLRT,
                                                     _Float16* __restrict__ C,
                                                     float* __restrict__ el,
                                                     float* __restrict__ er, int M) {
    const int N = 32;
    int lane = threadIdx.x & 63, w = threadIdx.x >> 6;
    int mr = blockIdx.x * 256 + w * 64;
    const _Float16* pa[4];
    const _Float16* pb[2];
    #pragma unroll
    for (int t = 0; t < 4; ++t) {
        int row = mr + t * 16 + (lane & 15);
        if (row > M - 1) row = M - 1;
        pa[t] = A + (size_t)row * K + (lane >> 4) * 8;
    }
    #pragma unroll
    for (int t = 0; t < 2; ++t) {
        int col = t * 16 + (lane & 15);
        pb[t] = BT + (size_t)col * K + (lane >> 4) * 8;
    }
    const _Float16* pe = WLRT + (size_t)(lane & 15) * K + (lane >> 4) * 8;
    f32x4 acc[4][2] = {};
    f32x4 acce[4] = {};
    #pragma unroll
    for (int k0 = 0; k0 < K; k0 += 32) {
        f16x8 a[4], b[2], be;
        #pragma unroll
        for (int t = 0; t < 4; ++t) a[t] = *(const f16x8*)(pa[t] + k0);
        #pragma unroll
        for (int t = 0; t < 2; ++t) b[t] = *(const f16x8*)(pb[t] + k0);
        be = *(const f16x8*)(pe + k0);
        #pragma unroll
        for (int i = 0; i < 4; ++i) {
            #pragma unroll
            for (int j = 0; j < 2; ++j)
                acc[i][j] = __builtin_amdgcn_mfma_f32_16x16x32_f16(a[i], b[j], acc[i][j], 0, 0, 0);
            acce[i] = __builtin_amdgcn_mfma_f32_16x16x32_f16(a[i], be, acce[i], 0, 0, 0);
        }
    }
    int c16 = lane & 15;
    #pragma unroll
    for (int i = 0; i < 4; ++i)
        #pragma unroll
        for (int r = 0; r < 4; ++r) {
            int row = mr + i * 16 + (lane >> 4) * 4 + r;
            if (row < M) {
                #pragma unroll
                for (int j = 0; j < 2; ++j)
                    C[(size_t)row * N + j * 16 + c16] = (_Float16)acc[i][j][r];
                if (c16 == 0) el[row] = acce[i][r];
                else if (c16 == 1) er[row] = acce[i][r];
            }
        }
}

// ---------- CSR scans ----------
__global__ __launch_bounds__(256) void k_scan1(const int* __restrict__ deg,
                                               int* __restrict__ bsum, int n) {
    int base = blockIdx.x * 1024;
    int t = threadIdx.x;
    int s = 0;
    #pragma unroll
    for (int i = 0; i < 4; ++i) {
        int idx = base + t * 4 + i;
        if (idx < n) s += deg[idx];
    }
    __shared__ int red[256];
    red[t] = s; __syncthreads();
    for (int off = 128; off; off >>= 1) {
        if (t < off) red[t] += red[t + off];
        __syncthreads();
    }
    if (t == 0) bsum[blockIdx.x] = red[0];
}
__global__ __launch_bounds__(256) void k_scan3(const int* __restrict__ deg,
                                               const int* __restrict__ bsum,
                                               int* __restrict__ row_ptr, int n, int E) {
    int base = blockIdx.x * 1024;
    int t = threadIdx.x;
    __shared__ int boff;
    if (t == 0) {
        int s = 0;
        for (int j = 0; j < blockIdx.x; ++j) s += bsum[j];
        boff = s;
        if (blockIdx.x == 0) row_ptr[n] = E;
    }
    int loc[4]; int s = 0;
    #pragma unroll
    for (int i = 0; i < 4; ++i) {
        int idx = base + t * 4 + i;
        loc[i] = (idx < n) ? deg[idx] : 0;
        s += loc[i];
    }
    __shared__ int part[256];
    part[t] = s; __syncthreads();
    for (int off = 1; off < 256; off <<= 1) {
        int v = (t >= off) ? part[t - off] : 0;
        __syncthreads();
        part[t] += v;
        __syncthreads();
    }
    int run = boff + part[t] - s;
    #pragma unroll
    for (int i = 0; i < 4; ++i) {
        int idx = base + t * 4 + i;
        if (idx < n) row_ptr[idx] = run;
        run += loc[i];
    }
}

// ---------- fused softmax aggregation, H=8,C=32: single pass, fp8, unroll 4 ----------
__global__ __launch_bounds__(256) void k_fused256(const int* __restrict__ row_ptr,
                                                  const int* __restrict__ csrc,
                                                  const float* __restrict__ el,
                                                  const float* __restrict__ er,
                                                  const unsigned char* __restrict__ ft8,
                                                  const float* __restrict__ b,
                                                  _Float16* __restrict__ out, int n) {
    int wave = threadIdx.x >> 6;
    int lane = threadIdx.x & 63;
    int v = blockIdx.x * 4 + wave;
    if (v >= n) return;
    int g = lane >> 4;            // edge slot 0..3
    int l16 = lane & 15;          // channel group: 16 ch each
    int h = l16 >> 1;             // head (2 lanes per head)
    float erv = er[v * 8 + h];
    const float* elh = el + h;
    int e0 = row_ptr[v], e1 = row_ptr[v + 1];
    float s = 0.f;
    float a[16] = {};
    int k = e0 + g;
    for (; k + 12 < e1; k += 16) {       // 4 edges issued before decode/FMA
        int sn0 = csrc[k];
        int sn1 = csrc[k + 4];
        int sn2 = csrc[k + 8];
        int sn3 = csrc[k + 12];
        float ev0 = elh[sn0 * 8] + erv;
        float ev1 = elh[sn1 * 8] + erv;
        float ev2 = elh[sn2 * 8] + erv;
        float ev3 = elh[sn3 * 8] + erv;
        uint4 q0 = *(const uint4*)(ft8 + ((size_t)sn0 << 8) + l16 * 16);
        uint4 q1 = *(const uint4*)(ft8 + ((size_t)sn1 << 8) + l16 * 16);
        uint4 q2 = *(const uint4*)(ft8 + ((size_t)sn2 << 8) + l16 * 16);
        uint4 q3 = *(const uint4*)(ft8 + ((size_t)sn3 << 8) + l16 * 16);
        ev0 = ev0 > 0.f ? ev0 : 0.2f * ev0;
        ev1 = ev1 > 0.f ? ev1 : 0.2f * ev1;
        ev2 = ev2 > 0.f ? ev2 : 0.2f * ev2;
        ev3 = ev3 > 0.f ? ev3 : 0.2f * ev3;
        float w0 = __expf(ev0), w1 = __expf(ev1), w2 = __expf(ev2), w3 = __expf(ev3);
        s += (w0 + w1) + (w2 + w3);
        float f[16];
        fp8x4_to_f32(q0.x, f);     fp8x4_to_f32(q0.y, f + 4);
        fp8x4_to_f32(q0.z, f + 8); fp8x4_to_f32(q0.w, f + 12);
        #pragma unroll
        for (int j = 0; j < 16; ++j) a[j] += w0 * f[j];
        fp8x4_to_f32(q1.x, f);     fp8x4_to_f32(q1.y, f + 4);
        fp8x4_to_f32(q1.z, f + 8); fp8x4_to_f32(q1.w, f + 12);
        #pragma unroll
        for (int j = 0; j < 16; ++j) a[j] += w1 * f[j];
        fp8x4_to_f32(q2.x, f);     fp8x4_to_f32(q2.y, f + 4);
        fp8x4_to_f32(q2.z, f + 8); fp8x4_to_f32(q2.w, f + 12);
        #pragma unroll
        for (int j = 0; j < 16; ++j) a[j] += w2 * f[j];
        fp8x4_to_f32(q3.x, f);     fp8x4_to_f32(q3.y, f + 4);
        fp8x4_to_f32(q3.z, f + 8); fp8x4_to_f32(q3.w, f + 12);
        #pragma unroll
        for (int j = 0; j < 16; ++j) a[j] += w3 * f[j];
    }
    for (; k < e1; k += 4) {
        int sn = csrc[k];
        float ev = elh[sn * 8] + erv;
        ev = ev > 0.f ? ev : 0.2f * ev;
        float w = __expf(ev);
        s += w;
        uint4 q = *(const uint4*)(ft8 + ((size_t)sn << 8) + l16 * 16);
        float f[16];
        fp8x4_to_f32(q.x, f);     fp8x4_to_f32(q.y, f + 4);
        fp8x4_to_f32(q.z, f + 8); fp8x4_to_f32(q.w, f + 12);
        #pragma unroll
        for (int j = 0; j < 16; ++j) a[j] += w * f[j];
    }
    s += __shfl_xor(s, 16, 64);
    s += __shfl_xor(s, 32, 64);
    #pragma unroll
    for (int j = 0; j < 16; ++j) {
        a[j] += __shfl_xor(a[j], 16, 64);
        a[j] += __shfl_xor(a[j], 32, 64);
    }
    if (g == 0) {
        float inv = s > 0.f ? 1.f / s : 0.f;
        const float* bp = b + l16 * 16;
        f16x8 o0, o1;
        #pragma unroll
        for (int j = 0; j < 8; ++j) o0[j] = (_Float16)fmaxf(a[j] * inv + bp[j], 0.f);
        #pragma unroll
        for (int j = 0; j < 8; ++j) o1[j] = (_Float16)fmaxf(a[8 + j] * inv + bp[8 + j], 0.f);
        _Float16* op = out + ((size_t)v << 8) + l16 * 16;
        *(f16x8*)op = o0;
        *(f16x8*)(op + 8) = o1;
    }
}

// ---------- fused aggregation, H=1,C=32 (layer 2) + class softmax (fp16 ft) ----------
__global__ __launch_bounds__(256) void k_fused_out(const int* __restrict__ row_ptr,
                                                   const int* __restrict__ csrc,
                                                   const float* __restrict__ el,
                                                   const float* __restrict__ er,
                                                   const _Float16* __restrict__ ft,
                                                   const float* __restrict__ b,
                                                   float* __restrict__ out, int n) {
    int v = blockIdx.x * 16 + (threadIdx.x >> 4);
    int sub = threadIdx.x & 15;
    int g = sub >> 2;             // edge slot 0..3
    int l4 = sub & 3;             // channel group: 8 ch each
    if (v >= n) return;
    float erv = er[v];
    int e0 = row_ptr[v], e1 = row_ptr[v + 1];
    float s = 0.f;
    float a[8] = {};
    for (int k = e0 + g; k < e1; k += 4) {
        int sn = csrc[k];
        float ev = el[sn] + erv;
        ev = ev > 0.f ? ev : 0.2f * ev;
        float w = __expf(ev);
        s += w;
        f16x8 f = *(const f16x8*)(ft + (sn << 5) + l4 * 8);
        #pragma unroll
        for (int j = 0; j < 8; ++j) a[j] += w * (float)f[j];
    }
    s += __shfl_xor(s, 4, 64);
    s += __shfl_xor(s, 8, 64);
    #pragma unroll
    for (int j = 0; j < 8; ++j) {
        a[j] += __shfl_xor(a[j], 4, 64);
        a[j] += __shfl_xor(a[j], 8, 64);
    }
    float inv = s > 0.f ? 1.f / s : 0.f;
    const float* bp = b + l4 * 8;
    float val[8];
    float mx = -INFINITY;
    #pragma unroll
    for (int j = 0; j < 8; ++j) {
        val[j] = fmaxf(a[j] * inv + bp[j], 0.f);
        mx = fmaxf(mx, val[j]);
    }
    mx = fmaxf(mx, __shfl_xor(mx, 1, 64));
    mx = fmaxf(mx, __shfl_xor(mx, 2, 64));
    float ex[8];
    float sum = 0.f;
    #pragma unroll
    for (int j = 0; j < 8; ++j) { ex[j] = __expf(val[j] - mx); sum += ex[j]; }
    sum += __shfl_xor(sum, 1, 64);
    sum += __shfl_xor(sum, 2, 64);
    float isum = 1.f / sum;
    if (g == 0) {
        float* op = out + ((size_t)v << 5) + l4 * 8;
        *(float4*)op = make_float4(ex[0] * isum, ex[1] * isum, ex[2] * isum, ex[3] * isum);
        *(float4*)(op + 4) = make_float4(ex[4] * isum, ex[5] * isum, ex[6] * isum, ex[7] * isum);
    }
}

extern "C" void kernel_launch(void* const* d_in, const int* in_sizes, int n_in,
                              void* d_out, int out_size, void* d_ws, size_t ws_size,
                              hipStream_t stream) {
    const float* x  = (const float*)d_in[0];
    const int* src  = (const int*)d_in[1];
    const int* dst  = (const int*)d_in[2];
    const float* W0 = (const float*)d_in[3];
    const float* al0 = (const float*)d_in[4];
    const float* ar0 = (const float*)d_in[5];
    const float* b0  = (const float*)d_in[6];
    const float* W1 = (const float*)d_in[7];
    const float* al1 = (const float*)d_in[8];
    const float* ar1 = (const float*)d_in[9];
    const float* b1  = (const float*)d_in[10];
    const float* W2 = (const float*)d_in[11];
    const float* al2 = (const float*)d_in[12];
    const float* ar2 = (const float*)d_in[13];
    const float* b2  = (const float*)d_in[14];
    float* out = (float*)d_out;

    const int n = in_sizes[0] / IN_FEATS;   // 50000
    const int E = in_sizes[1];              // 800000

    // ---- workspace carve (256B-aligned) ----
    char* p = (char*)d_ws;
    auto alloc = [&](size_t bytes) {
        void* r = (void*)p;
        p += (bytes + 255) & ~(size_t)255;
        return r;
    };
    unsigned char* ft8 = (unsigned char*)alloc((size_t)n * 256);   // GEMM out (fp8)
    _Float16* h16   = (_Float16*)alloc((size_t)n * 256 * 2);       // agg out
    _Float16* ft16  = (_Float16*)alloc((size_t)n * 32 * 2);        // layer-2 GEMM out
    _Float16* W0T   = (_Float16*)alloc((size_t)256 * 128 * 2);
    _Float16* W1T   = (_Float16*)alloc((size_t)256 * 256 * 2);
    _Float16* W2T   = (_Float16*)alloc((size_t)32 * 256 * 2);
    _Float16* WLR0  = (_Float16*)alloc((size_t)16 * 128 * 2);
    _Float16* WLR1  = (_Float16*)alloc((size_t)16 * 256 * 2);
    _Float16* WLR2  = (_Float16*)alloc((size_t)16 * 256 * 2);
    float* el       = (float*)alloc((size_t)n * 8 * 4);
    float* er       = (float*)alloc((size_t)n * 8 * 4);
    int* deg        = (int*)alloc((size_t)n * 4);
    int* fill       = (int*)alloc((size_t)n * 4);   // adjacent to deg: one memset
    int* row_ptr    = (int*)alloc((size_t)(n + 1) * 4);
    int* csrc       = (int*)alloc((size_t)E * 4);
    int* bsum       = (int*)alloc((size_t)64 * 4);

    const int EB = (E + 255) / 256;          // 3125
    const int NBCH = (n + 1023) / 1024;      // 49
    const int GB = (n + 63) / 64;            // 782
    const int GB32 = (n + 255) / 256;
    const int FB = (n + 3) / 4;
    const int OB = (n + 15) / 16;

    // ---- memset deg+fill (adjacent) ----
    hipMemsetAsync(deg, 0, (size_t)((char*)fill - (char*)deg) + (size_t)n * 4, stream);

    // ---- weight prep ∥ degree count ----
    k_degprep<<<456 + EB, 256, 0, stream>>>(W0, W1, W2, al0, ar0, al1, ar1, al2, ar2,
                                            W0T, W1T, W2T, WLR0, WLR1, WLR2,
                                            dst, deg, E);
    k_scan1<<<NBCH, 256, 0, stream>>>(deg, bsum, n);
    k_scan3<<<NBCH, 256, 0, stream>>>(deg, bsum, row_ptr, n, E);

    // ---- layer-0 GEMM ∥ CSR fill ----
    k_gemm0_fill<<<GB + EB, 256, 0, stream>>>(x, W0T, WLR0, ft8, el, er, n, GB,
                                              dst, src, row_ptr, fill, csrc, E);
    k_fused256<<<FB, 256, 0, stream>>>(row_ptr, csrc, el, er, ft8, b0, h16, n);

    // ---- layer 1 ----
    k_mfma_gemm<256><<<GB, 256, 0, stream>>>(h16, W1T, WLR1, ft8, el, er, n);
    k_fused256<<<FB, 256, 0, stream>>>(row_ptr, csrc, el, er, ft8, b1, h16, n);

    // ---- layer 2 + class softmax ----
    k_mfma_gemm32<256><<<GB32, 256, 0, stream>>>(h16, W2T, WLR2, ft16, el, er, n);
    k_fused_out<<<OB, 256, 0, stream>>>(row_ptr, csrc, el, er, ft16, b2, out, n);
}

// Round 12
// 299.371 us; speedup vs baseline: 1.3717x; 1.0793x over previous
//
#include <hip/hip_runtime.h>
#include <hip/hip_fp16.h>
#include <cstdint>
#include <cstddef>

// GAT 3-layer forward for MI355X — round 12.
// Changes vs round 11 (323us):
//  * rank[e] computed in k_degprep from the degree atomic's RETURN VALUE
//    (was discarded; rank write is coalesced). Fill branch loses its atomic:
//    pure scatter csrc[row_ptr[d]+rank[e]] = src[e] — one memory round trip
//    per edge instead of two (fill was latency-bound: VALU 5%, HBM 18%).
//  * fill branch: 4 edges/thread (occupancy capped ~5 blk/CU by GEMM branch
//    footprint -> per-thread ILP is the remaining scatter lever).

#define IN_FEATS 128

typedef _Float16 f16x8 __attribute__((ext_vector_type(8)));
typedef float f32x4 __attribute__((ext_vector_type(4)));

// ---------- fp8 helpers (HW cvt; self-consistent encode/decode) ----------
__device__ __forceinline__ unsigned char f32_to_fp8(float f) {
    int p = __builtin_amdgcn_cvt_pk_fp8_f32(f, 0.f, 0, false);
    return (unsigned char)(p & 0xff);
}
__device__ __forceinline__ void fp8x4_to_f32(unsigned w, float* o) {
    o[0] = __builtin_amdgcn_cvt_f32_fp8(w, 0);
    o[1] = __builtin_amdgcn_cvt_f32_fp8(w, 1);
    o[2] = __builtin_amdgcn_cvt_f32_fp8(w, 2);
    o[3] = __builtin_amdgcn_cvt_f32_fp8(w, 3);
}

// ---------- fused: weight prep (blocks 0..455) ∥ degree+rank (rest) ----------
__global__ __launch_bounds__(256) void k_degprep(
    const float* __restrict__ W0, const float* __restrict__ W1, const float* __restrict__ W2,
    const float* __restrict__ al0, const float* __restrict__ ar0,
    const float* __restrict__ al1, const float* __restrict__ ar1,
    const float* __restrict__ al2, const float* __restrict__ ar2,
    _Float16* __restrict__ W0T, _Float16* __restrict__ W1T, _Float16* __restrict__ W2T,
    _Float16* __restrict__ WLR0, _Float16* __restrict__ WLR1, _Float16* __restrict__ WLR2,
    const int* __restrict__ dst, int* __restrict__ deg, int* __restrict__ rank, int E) {
    int bid = blockIdx.x, t = threadIdx.x;
    if (bid >= 456) {                      // degree count + rank (rank write coalesced)
        int e = (bid - 456) * 256 + t;
        if (e < E) rank[e] = atomicAdd(deg + dst[e], 1);
        return;
    }
    if (bid < 128) {                       // W0T [256][128]
        int i = bid * 256 + t;
        int nn = i >> 7, kk = i & 127;
        W0T[i] = (_Float16)W0[(size_t)kk * 256 + nn];
    } else if (bid < 384) {                // W1T [256][256]
        int i = (bid - 128) * 256 + t;
        int nn = i >> 8, kk = i & 255;
        W1T[i] = (_Float16)W1[(size_t)kk * 256 + nn];
    } else if (bid < 416) {                // W2T [32][256]
        int i = (bid - 384) * 256 + t;
        int nn = i >> 8, kk = i & 255;
        W2T[i] = (_Float16)W2[(size_t)kk * 32 + nn];
    } else if (bid < 424) {                // WLR0 [16][128]
        int i = (bid - 416) * 256 + t;
        int j = i >> 7, k = i & 127;
        int h = j & 7;
        const float* av = (j < 8) ? al0 : ar0;
        float sum = 0.f;
        #pragma unroll 8
        for (int c = 0; c < 32; ++c) sum += W0[(size_t)k * 256 + h * 32 + c] * av[h * 32 + c];
        WLR0[i] = (_Float16)sum;
    } else if (bid < 440) {                // WLR1 [16][256]
        int i = (bid - 424) * 256 + t;
        int j = i >> 8, k = i & 255;
        int h = j & 7;
        const float* av = (j < 8) ? al1 : ar1;
        float sum = 0.f;
        #pragma unroll 8
        for (int c = 0; c < 32; ++c) sum += W1[(size_t)k * 256 + h * 32 + c] * av[h * 32 + c];
        WLR1[i] = (_Float16)sum;
    } else {                               // WLR2 [16][256]
        int i = (bid - 440) * 256 + t;
        int j = i >> 8, k = i & 255;
        float sum = 0.f;
        if (j < 2) {
            const float* av = (j == 0) ? al2 : ar2;
            #pragma unroll 8
            for (int c = 0; c < 32; ++c) sum += W2[(size_t)k * 32 + c] * av[c];
        }
        WLR2[i] = (_Float16)sum;
    }
}

// ---------- fused: layer-0 GEMM (blocks < GB) ∥ atomic-free CSR fill ----------
__global__ __launch_bounds__(256) void k_gemm0_fill(
    const float* __restrict__ A, const _Float16* __restrict__ BT,
    const _Float16* __restrict__ WLRT, unsigned char* __restrict__ C8,
    float* __restrict__ el, float* __restrict__ er, int M, int GB,
    const int* __restrict__ dst, const int* __restrict__ src,
    const int* __restrict__ row_ptr, const int* __restrict__ rank,
    int* __restrict__ csrc, int E) {
    const int K = 128, N = 256, LDA = K + 8;
    __shared__ _Float16 As[64 * LDA];
    int tid = threadIdx.x;
    if ((int)blockIdx.x >= GB) {           // ---- fill branch: 4 edges/thread ----
        int base = ((int)blockIdx.x - GB) * 1024 + tid;
        #pragma unroll
        for (int i = 0; i < 4; ++i) {
            int e = base + i * 256;
            if (e < E) {
                int d = dst[e];
                csrc[row_ptr[d] + rank[e]] = src[e];
            }
        }
        return;
    }
    // ---- GEMM branch (K=128, A fp32 cast in staging) ----
    int lane = tid & 63, wc = tid >> 6;
    int mr = blockIdx.x * 64;
    #pragma unroll
    for (int it = 0; it < K / 32; ++it) {
        int idx = (it * 256 + tid) * 8;
        int row = idx / K, col = idx % K;
        int rowg = mr + row; if (rowg > M - 1) rowg = M - 1;
        float4 u0 = *(const float4*)(A + (size_t)rowg * K + col);
        float4 u1 = *(const float4*)(A + (size_t)rowg * K + col + 4);
        f16x8 v;
        v[0] = (_Float16)u0.x; v[1] = (_Float16)u0.y;
        v[2] = (_Float16)u0.z; v[3] = (_Float16)u0.w;
        v[4] = (_Float16)u1.x; v[5] = (_Float16)u1.y;
        v[6] = (_Float16)u1.z; v[7] = (_Float16)u1.w;
        *(f16x8*)(As + row * LDA + col) = v;
    }
    __syncthreads();
    const _Float16* pb[4];
    #pragma unroll
    for (int j = 0; j < 4; ++j) {
        int col = wc * 64 + j * 16 + (lane & 15);
        pb[j] = BT + (size_t)col * K + (lane >> 4) * 8;
    }
    const _Float16* pe = WLRT + (size_t)(lane & 15) * K + (lane >> 4) * 8;
    const _Float16* pa = As + (lane & 15) * LDA + (lane >> 4) * 8;
    f32x4 acc[4][4] = {};
    f32x4 acce[4] = {};
    #pragma unroll
    for (int k0 = 0; k0 < K; k0 += 32) {
        f16x8 a[4], b[4];
        #pragma unroll
        for (int t = 0; t < 4; ++t) a[t] = *(const f16x8*)(pa + t * 16 * LDA + k0);
        #pragma unroll
        for (int t = 0; t < 4; ++t) b[t] = *(const f16x8*)(pb[t] + k0);
        #pragma unroll
        for (int i = 0; i < 4; ++i)
            #pragma unroll
            for (int j = 0; j < 4; ++j)
                acc[i][j] = __builtin_amdgcn_mfma_f32_16x16x32_f16(a[i], b[j], acc[i][j], 0, 0, 0);
        if (wc == 3) {
            f16x8 be = *(const f16x8*)(pe + k0);
            #pragma unroll
            for (int i = 0; i < 4; ++i)
                acce[i] = __builtin_amdgcn_mfma_f32_16x16x32_f16(a[i], be, acce[i], 0, 0, 0);
        }
    }
    #pragma unroll
    for (int i = 0; i < 4; ++i)
        #pragma unroll
        for (int j = 0; j < 4; ++j)
            #pragma unroll
            for (int r = 0; r < 4; ++r) {
                int row = mr + i * 16 + (lane >> 4) * 4 + r;
                int col = wc * 64 + j * 16 + (lane & 15);
                if (row < M) C8[(size_t)row * N + col] = f32_to_fp8(acc[i][j][r]);
            }
    if (wc == 3) {
        int c16 = lane & 15;
        #pragma unroll
        for (int i = 0; i < 4; ++i)
            #pragma unroll
            for (int r = 0; r < 4; ++r) {
                int row = mr + i * 16 + (lane >> 4) * 4 + r;
                if (row < M) {
                    if (c16 < 8) el[row * 8 + c16] = acce[i][r];
                    else         er[row * 8 + (c16 - 8)] = acce[i][r];
                }
            }
    }
}

// ---------- MFMA GEMM, N=256 (layer 1), fp16 A, fp8 out; wave 3 emits el/er ----------
template <int K>
__global__ __launch_bounds__(256) void k_mfma_gemm(const _Float16* __restrict__ A,
                                                   const _Float16* __restrict__ BT,
                                                   const _Float16* __restrict__ WLRT,
                                                   unsigned char* __restrict__ C8,
                                                   float* __restrict__ el,
                                                   float* __restrict__ er, int M) {
    const int N = 256;
    const int LDA = K + 8;
    __shared__ _Float16 As[64 * LDA];
    int tid = threadIdx.x;
    int lane = tid & 63, wc = tid >> 6;
    int mr = blockIdx.x * 64;
    #pragma unroll
    for (int it = 0; it < K / 32; ++it) {
        int idx = (it * 256 + tid) * 8;
        int row = idx / K, col = idx % K;
        int rowg = mr + row; if (rowg > M - 1) rowg = M - 1;
        f16x8 v = *(const f16x8*)(A + (size_t)rowg * K + col);
        *(f16x8*)(As + row * LDA + col) = v;
    }
    __syncthreads();
    const _Float16* pb[4];
    #pragma unroll
    for (int j = 0; j < 4; ++j) {
        int col = wc * 64 + j * 16 + (lane & 15);
        pb[j] = BT + (size_t)col * K + (lane >> 4) * 8;
    }
    const _Float16* pe = WLRT + (size_t)(lane & 15) * K + (lane >> 4) * 8;
    const _Float16* pa = As + (lane & 15) * LDA + (lane >> 4) * 8;
    f32x4 acc[4][4] = {};
    f32x4 acce[4] = {};
    #pragma unroll
    for (int k0 = 0; k0 < K; k0 += 32) {
        f16x8 a[4], b[4];
        #pragma unroll
        for (int t = 0; t < 4; ++t) a[t] = *(const f16x8*)(pa + t * 16 * LDA + k0);
        #pragma unroll
        for (int t = 0; t < 4; ++t) b[t] = *(const f16x8*)(pb[t] + k0);
        #pragma unroll
        for (int i = 0; i < 4; ++i)
            #pragma unroll
            for (int j = 0; j < 4; ++j)
                acc[i][j] = __builtin_amdgcn_mfma_f32_16x16x32_f16(a[i], b[j], acc[i][j], 0, 0, 0);
        if (wc == 3) {
            f16x8 be = *(const f16x8*)(pe + k0);
            #pragma unroll
            for (int i = 0; i < 4; ++i)
                acce[i] = __builtin_amdgcn_mfma_f32_16x16x32_f16(a[i], be, acce[i], 0, 0, 0);
        }
    }
    #pragma unroll
    for (int i = 0; i < 4; ++i)
        #pragma unroll
        for (int j = 0; j < 4; ++j)
            #pragma unroll
            for (int r = 0; r < 4; ++r) {
                int row = mr + i * 16 + (lane >> 4) * 4 + r;
                int col = wc * 64 + j * 16 + (lane & 15);
                if (row < M) C8[(size_t)row * N + col] = f32_to_fp8(acc[i][j][r]);
            }
    if (wc == 3) {
        int c16 = lane & 15;
        #pragma unroll
        for (int i = 0; i < 4; ++i)
            #pragma unroll
            for (int r = 0; r < 4; ++r) {
                int row = mr + i * 16 + (lane >> 4) * 4 + r;
                if (row < M) {
                    if (c16 < 8) el[row * 8 + c16] = acce[i][r];
                    else         er[row * 8 + (c16 - 8)] = acce[i][r];
                }
            }
    }
}

// ---------- MFMA GEMM, N=32 (layer 2), fp16 out, fused el/er via WLR2 ----------
template <int K>
__global__ __launch_bounds__(256) void k_mfma_gemm32(const _Float16* __restrict__ A,
                                                     const _Float16* __restrict__ BT,
                                                     const _Float16* __restrict__ WLRT,
                                                     _Float16* __restrict__ C,
                                                     float* __restrict__ el,
                                                     float* __restrict__ er, int M) {
    const int N = 32;
    int lane = threadIdx.x & 63, w = threadIdx.x >> 6;
    int mr = blockIdx.x * 256 + w * 64;
    const _Float16* pa[4];
    const _Float16* pb[2];
    #pragma unroll
    for (int t = 0; t < 4; ++t) {
        int row = mr + t * 16 + (lane & 15);
        if (row > M - 1) row = M - 1;
        pa[t] = A + (size_t)row * K + (lane >> 4) * 8;
    }
    #pragma unroll
    for (int t = 0; t < 2; ++t) {
        int col = t * 16 + (lane & 15);
        pb[t] = BT + (size_t)col * K + (lane >> 4) * 8;
    }
    const _Float16* pe = WLRT + (size_t)(lane & 15) * K + (lane >> 4) * 8;
    f32x4 acc[4][2] = {};
    f32x4 acce[4] = {};
    #pragma unroll
    for (int k0 = 0; k0 < K; k0 += 32) {
        f16x8 a[4], b[2], be;
        #pragma unroll
        for (int t = 0; t < 4; ++t) a[t] = *(const f16x8*)(pa[t] + k0);
        #pragma unroll
        for (int t = 0; t < 2; ++t) b[t] = *(const f16x8*)(pb[t] + k0);
        be = *(const f16x8*)(pe + k0);
        #pragma unroll
        for (int i = 0; i < 4; ++i) {
            #pragma unroll
            for (int j = 0; j < 2; ++j)
                acc[i][j] = __builtin_amdgcn_mfma_f32_16x16x32_f16(a[i], b[j], acc[i][j], 0, 0, 0);
            acce[i] = __builtin_amdgcn_mfma_f32_16x16x32_f16(a[i], be, acce[i], 0, 0, 0);
        }
    }
    int c16 = lane & 15;
    #pragma unroll
    for (int i = 0; i < 4; ++i)
        #pragma unroll
        for (int r = 0; r < 4; ++r) {
            int row = mr + i * 16 + (lane >> 4) * 4 + r;
            if (row < M) {
                #pragma unroll
                for (int j = 0; j < 2; ++j)
                    C[(size_t)row * N + j * 16 + c16] = (_Float16)acc[i][j][r];
                if (c16 == 0) el[row] = acce[i][r];
                else if (c16 == 1) er[row] = acce[i][r];
            }
        }
}

// ---------- CSR scans ----------
__global__ __launch_bounds__(256) void k_scan1(const int* __restrict__ deg,
                                               int* __restrict__ bsum, int n) {
    int base = blockIdx.x * 1024;
    int t = threadIdx.x;
    int s = 0;
    #pragma unroll
    for (int i = 0; i < 4; ++i) {
        int idx = base + t * 4 + i;
        if (idx < n) s += deg[idx];
    }
    __shared__ int red[256];
    red[t] = s; __syncthreads();
    for (int off = 128; off; off >>= 1) {
        if (t < off) red[t] += red[t + off];
        __syncthreads();
    }
    if (t == 0) bsum[blockIdx.x] = red[0];
}
__global__ __launch_bounds__(256) void k_scan3(const int* __restrict__ deg,
                                               const int* __restrict__ bsum,
                                               int* __restrict__ row_ptr, int n, int E) {
    int base = blockIdx.x * 1024;
    int t = threadIdx.x;
    __shared__ int boff;
    if (t == 0) {
        int s = 0;
        for (int j = 0; j < blockIdx.x; ++j) s += bsum[j];
        boff = s;
        if (blockIdx.x == 0) row_ptr[n] = E;
    }
    int loc[4]; int s = 0;
    #pragma unroll
    for (int i = 0; i < 4; ++i) {
        int idx = base + t * 4 + i;
        loc[i] = (idx < n) ? deg[idx] : 0;
        s += loc[i];
    }
    __shared__ int part[256];
    part[t] = s; __syncthreads();
    for (int off = 1; off < 256; off <<= 1) {
        int v = (t >= off) ? part[t - off] : 0;
        __syncthreads();
        part[t] += v;
        __syncthreads();
    }
    int run = boff + part[t] - s;
    #pragma unroll
    for (int i = 0; i < 4; ++i) {
        int idx = base + t * 4 + i;
        if (idx < n) row_ptr[idx] = run;
        run += loc[i];
    }
}

// ---------- fused softmax aggregation, H=8,C=32: single pass, fp8, unroll 4 ----------
__global__ __launch_bounds__(256) void k_fused256(const int* __restrict__ row_ptr,
                                                  const int* __restrict__ csrc,
                                                  const float* __restrict__ el,
                                                  const float* __restrict__ er,
                                                  const unsigned char* __restrict__ ft8,
                                                  const float* __restrict__ b,
                                                  _Float16* __restrict__ out, int n) {
    int wave = threadIdx.x >> 6;
    int lane = threadIdx.x & 63;
    int v = blockIdx.x * 4 + wave;
    if (v >= n) return;
    int g = lane >> 4;            // edge slot 0..3
    int l16 = lane & 15;          // channel group: 16 ch each
    int h = l16 >> 1;             // head (2 lanes per head)
    float erv = er[v * 8 + h];
    const float* elh = el + h;
    int e0 = row_ptr[v], e1 = row_ptr[v + 1];
    float s = 0.f;
    float a[16] = {};
    int k = e0 + g;
    for (; k + 12 < e1; k += 16) {       // 4 edges issued before decode/FMA
        int sn0 = csrc[k];
        int sn1 = csrc[k + 4];
        int sn2 = csrc[k + 8];
        int sn3 = csrc[k + 12];
        float ev0 = elh[sn0 * 8] + erv;
        float ev1 = elh[sn1 * 8] + erv;
        float ev2 = elh[sn2 * 8] + erv;
        float ev3 = elh[sn3 * 8] + erv;
        uint4 q0 = *(const uint4*)(ft8 + ((size_t)sn0 << 8) + l16 * 16);
        uint4 q1 = *(const uint4*)(ft8 + ((size_t)sn1 << 8) + l16 * 16);
        uint4 q2 = *(const uint4*)(ft8 + ((size_t)sn2 << 8) + l16 * 16);
        uint4 q3 = *(const uint4*)(ft8 + ((size_t)sn3 << 8) + l16 * 16);
        ev0 = ev0 > 0.f ? ev0 : 0.2f * ev0;
        ev1 = ev1 > 0.f ? ev1 : 0.2f * ev1;
        ev2 = ev2 > 0.f ? ev2 : 0.2f * ev2;
        ev3 = ev3 > 0.f ? ev3 : 0.2f * ev3;
        float w0 = __expf(ev0), w1 = __expf(ev1), w2 = __expf(ev2), w3 = __expf(ev3);
        s += (w0 + w1) + (w2 + w3);
        float f[16];
        fp8x4_to_f32(q0.x, f);     fp8x4_to_f32(q0.y, f + 4);
        fp8x4_to_f32(q0.z, f + 8); fp8x4_to_f32(q0.w, f + 12);
        #pragma unroll
        for (int j = 0; j < 16; ++j) a[j] += w0 * f[j];
        fp8x4_to_f32(q1.x, f);     fp8x4_to_f32(q1.y, f + 4);
        fp8x4_to_f32(q1.z, f + 8); fp8x4_to_f32(q1.w, f + 12);
        #pragma unroll
        for (int j = 0; j < 16; ++j) a[j] += w1 * f[j];
        fp8x4_to_f32(q2.x, f);     fp8x4_to_f32(q2.y, f + 4);
        fp8x4_to_f32(q2.z, f + 8); fp8x4_to_f32(q2.w, f + 12);
        #pragma unroll
        for (int j = 0; j < 16; ++j) a[j] += w2 * f[j];
        fp8x4_to_f32(q3.x, f);     fp8x4_to_f32(q3.y, f + 4);
        fp8x4_to_f32(q3.z, f + 8); fp8x4_to_f32(q3.w, f + 12);
        #pragma unroll
        for (int j = 0; j < 16; ++j) a[j] += w3 * f[j];
    }
    for (; k < e1; k += 4) {
        int sn = csrc[k];
        float ev = elh[sn * 8] + erv;
        ev = ev > 0.f ? ev : 0.2f * ev;
        float w = __expf(ev);
        s += w;
        uint4 q = *(const uint4*)(ft8 + ((size_t)sn << 8) + l16 * 16);
        float f[16];
        fp8x4_to_f32(q.x, f);     fp8x4_to_f32(q.y, f + 4);
        fp8x4_to_f32(q.z, f + 8); fp8x4_to_f32(q.w, f + 12);
        #pragma unroll
        for (int j = 0; j < 16; ++j) a[j] += w * f[j];
    }
    s += __shfl_xor(s, 16, 64);
    s += __shfl_xor(s, 32, 64);
    #pragma unroll
    for (int j = 0; j < 16; ++j) {
        a[j] += __shfl_xor(a[j], 16, 64);
        a[j] += __shfl_xor(a[j], 32, 64);
    }
    if (g == 0) {
        float inv = s > 0.f ? 1.f / s : 0.f;
        const float* bp = b + l16 * 16;
        f16x8 o0, o1;
        #pragma unroll
        for (int j = 0; j < 8; ++j) o0[j] = (_Float16)fmaxf(a[j] * inv + bp[j], 0.f);
        #pragma unroll
        for (int j = 0; j < 8; ++j) o1[j] = (_Float16)fmaxf(a[8 + j] * inv + bp[8 + j], 0.f);
        _Float16* op = out + ((size_t)v << 8) + l16 * 16;
        *(f16x8*)op = o0;
        *(f16x8*)(op + 8) = o1;
    }
}

// ---------- fused aggregation, H=1,C=32 (layer 2) + class softmax (fp16 ft) ----------
__global__ __launch_bounds__(256) void k_fused_out(const int* __restrict__ row_ptr,
                                                   const int* __restrict__ csrc,
                                                   const float* __restrict__ el,
                                                   const float* __restrict__ er,
                                                   const _Float16* __restrict__ ft,
                                                   const float* __restrict__ b,
                                                   float* __restrict__ out, int n) {
    int v = blockIdx.x * 16 + (threadIdx.x >> 4);
    int sub = threadIdx.x & 15;
    int g = sub >> 2;             // edge slot 0..3
    int l4 = sub & 3;             // channel group: 8 ch each
    if (v >= n) return;
    float erv = er[v];
    int e0 = row_ptr[v], e1 = row_ptr[v + 1];
    float s = 0.f;
    float a[8] = {};
    for (int k = e0 + g; k < e1; k += 4) {
        int sn = csrc[k];
        float ev = el[sn] + erv;
        ev = ev > 0.f ? ev : 0.2f * ev;
        float w = __expf(ev);
        s += w;
        f16x8 f = *(const f16x8*)(ft + (sn << 5) + l4 * 8);
        #pragma unroll
        for (int j = 0; j < 8; ++j) a[j] += w * (float)f[j];
    }
    s += __shfl_xor(s, 4, 64);
    s += __shfl_xor(s, 8, 64);
    #pragma unroll
    for (int j = 0; j < 8; ++j) {
        a[j] += __shfl_xor(a[j], 4, 64);
        a[j] += __shfl_xor(a[j], 8, 64);
    }
    float inv = s > 0.f ? 1.f / s : 0.f;
    const float* bp = b + l4 * 8;
    float val[8];
    float mx = -INFINITY;
    #pragma unroll
    for (int j = 0; j < 8; ++j) {
        val[j] = fmaxf(a[j] * inv + bp[j], 0.f);
        mx = fmaxf(mx, val[j]);
    }
    mx = fmaxf(mx, __shfl_xor(mx, 1, 64));
    mx = fmaxf(mx, __shfl_xor(mx, 2, 64));
    float ex[8];
    float sum = 0.f;
    #pragma unroll
    for (int j = 0; j < 8; ++j) { ex[j] = __expf(val[j] - mx); sum += ex[j]; }
    sum += __shfl_xor(sum, 1, 64);
    sum += __shfl_xor(sum, 2, 64);
    float isum = 1.f / sum;
    if (g == 0) {
        float* op = out + ((size_t)v << 5) + l4 * 8;
        *(float4*)op = make_float4(ex[0] * isum, ex[1] * isum, ex[2] * isum, ex[3] * isum);
        *(float4*)(op + 4) = make_float4(ex[4] * isum, ex[5] * isum, ex[6] * isum, ex[7] * isum);
    }
}

extern "C" void kernel_launch(void* const* d_in, const int* in_sizes, int n_in,
                              void* d_out, int out_size, void* d_ws, size_t ws_size,
                              hipStream_t stream) {
    const float* x  = (const float*)d_in[0];
    const int* src  = (const int*)d_in[1];
    const int* dst  = (const int*)d_in[2];
    const float* W0 = (const float*)d_in[3];
    const float* al0 = (const float*)d_in[4];
    const float* ar0 = (const float*)d_in[5];
    const float* b0  = (const float*)d_in[6];
    const float* W1 = (const float*)d_in[7];
    const float* al1 = (const float*)d_in[8];
    const float* ar1 = (const float*)d_in[9];
    const float* b1  = (const float*)d_in[10];
    const float* W2 = (const float*)d_in[11];
    const float* al2 = (const float*)d_in[12];
    const float* ar2 = (const float*)d_in[13];
    const float* b2  = (const float*)d_in[14];
    float* out = (float*)d_out;

    const int n = in_sizes[0] / IN_FEATS;   // 50000
    const int E = in_sizes[1];              // 800000

    // ---- workspace carve (256B-aligned) ----
    char* p = (char*)d_ws;
    auto alloc = [&](size_t bytes) {
        void* r = (void*)p;
        p += (bytes + 255) & ~(size_t)255;
        return r;
    };
    unsigned char* ft8 = (unsigned char*)alloc((size_t)n * 256);   // GEMM out (fp8)
    _Float16* h16   = (_Float16*)alloc((size_t)n * 256 * 2);       // agg out
    _Float16* ft16  = (_Float16*)alloc((size_t)n * 32 * 2);        // layer-2 GEMM out
    _Float16* W0T   = (_Float16*)alloc((size_t)256 * 128 * 2);
    _Float16* W1T   = (_Float16*)alloc((size_t)256 * 256 * 2);
    _Float16* W2T   = (_Float16*)alloc((size_t)32 * 256 * 2);
    _Float16* WLR0  = (_Float16*)alloc((size_t)16 * 128 * 2);
    _Float16* WLR1  = (_Float16*)alloc((size_t)16 * 256 * 2);
    _Float16* WLR2  = (_Float16*)alloc((size_t)16 * 256 * 2);
    float* el       = (float*)alloc((size_t)n * 8 * 4);
    float* er       = (float*)alloc((size_t)n * 8 * 4);
    int* deg        = (int*)alloc((size_t)n * 4);
    int* row_ptr    = (int*)alloc((size_t)(n + 1) * 4);
    int* rank       = (int*)alloc((size_t)E * 4);
    int* csrc       = (int*)alloc((size_t)E * 4);
    int* bsum       = (int*)alloc((size_t)64 * 4);

    const int EB = (E + 255) / 256;          // 3125
    const int FILLB = (E + 1023) / 1024;     // 782 (4 edges/thread)
    const int NBCH = (n + 1023) / 1024;      // 49
    const int GB = (n + 63) / 64;            // 782
    const int GB32 = (n + 255) / 256;
    const int FB = (n + 3) / 4;
    const int OB = (n + 15) / 16;

    // ---- memset deg ----
    hipMemsetAsync(deg, 0, (size_t)n * 4, stream);

    // ---- weight prep ∥ degree+rank ----
    k_degprep<<<456 + EB, 256, 0, stream>>>(W0, W1, W2, al0, ar0, al1, ar1, al2, ar2,
                                            W0T, W1T, W2T, WLR0, WLR1, WLR2,
                                            dst, deg, rank, E);
    k_scan1<<<NBCH, 256, 0, stream>>>(deg, bsum, n);
    k_scan3<<<NBCH, 256, 0, stream>>>(deg, bsum, row_ptr, n, E);

    // ---- layer-0 GEMM ∥ atomic-free CSR fill ----
    k_gemm0_fill<<<GB + FILLB, 256, 0, stream>>>(x, W0T, WLR0, ft8, el, er, n, GB,
                                                 dst, src, row_ptr, rank, csrc, E);
    k_fused256<<<FB, 256, 0, stream>>>(row_ptr, csrc, el, er, ft8, b0, h16, n);

    // ---- layer 1 ----
    k_mfma_gemm<256><<<GB, 256, 0, stream>>>(h16, W1T, WLR1, ft8, el, er, n);
    k_fused256<<<FB, 256, 0, stream>>>(row_ptr, csrc, el, er, ft8, b1, h16, n);

    // ---- layer 2 + class softmax ----
    k_mfma_gemm32<256><<<GB32, 256, 0, stream>>>(h16, W2T, WLR2, ft16, el, er, n);
    k_fused_out<<<OB, 256, 0, stream>>>(row_ptr, csrc, el, er, ft16, b2, out, n);
}